// Round 20
// baseline (1476.566 us; speedup 1.0000x reference)
//
#include <hip/hip_runtime.h>
#include <cstdint>
#include <cstddef>

// Problem constants
#define BATCH 16
#define DIM 192
#define HEADS 6
#define HD 32
#define TOK 65536
#define QKV_D 576
#define MLP_D 768
#define SCALE 0.17677669529663687f  // 32^-0.5

#define CHQ 32768    // chunk for qkv+attention phase (8 images)

typedef __bf16 bf16x8 __attribute__((ext_vector_type(8)));
typedef float f32x4 __attribute__((ext_vector_type(4)));

// float -> bf16 (RNE) via hardware cvt (compiler fuses pairs into
// v_cvt_pk_bf16_f32; bitwise identical to manual round-to-nearest-even)
__device__ __forceinline__ unsigned short f2bf(float f) {
  union { __bf16 h; unsigned short u; } c;
  c.h = (__bf16)f;
  return c.u;
}

__device__ __forceinline__ float waveSum(float v) {
#pragma unroll
  for (int off = 32; off; off >>= 1) v += __shfl_xor(v, off, 64);
  return v;
}

// reduce across the 16 lanes sharing a C-row (lane>>4 fixed)
__device__ __forceinline__ float rowSum16(float v) {
  v += __shfl_xor(v, 1, 64);
  v += __shfl_xor(v, 2, 64);
  v += __shfl_xor(v, 4, 64);
  v += __shfl_xor(v, 8, 64);
  return v;
}

// global -> LDS direct (16B/lane). LDS dest wave-uniform base + lane*16.
#define GLD(SRC, DST)                                                     \
  __builtin_amdgcn_global_load_lds(                                       \
      (const __attribute__((address_space(1))) void*)(SRC),               \
      (__attribute__((address_space(3))) void*)(DST), 16, 0, 0)

// ---------------- small utility kernels ------------------------------------
__global__ __launch_bounds__(64) void zero_k(float* p) { p[threadIdx.x] = 0.f; }

__global__ __launch_bounds__(256) void cvt_k(const float* __restrict__ s,
                                             unsigned short* __restrict__ d,
                                             int n) {
  int i = ((blockIdx.x << 8) + threadIdx.x) << 2;
  if (i < n) {
    float4 v = *(const float4*)(s + i);
    d[i] = f2bf(v.x);
    d[i + 1] = f2bf(v.y);
    d[i + 2] = f2bf(v.z);
    d[i + 3] = f2bf(v.w);
  }
}

// qkv weights -> bf16 with Q rows (row%576 < 192) pre-scaled by SCALE
__global__ __launch_bounds__(256) void cvt_qkv_k(const float* __restrict__ s,
                                                 unsigned short* __restrict__ d) {
  int i = (blockIdx.x << 8) + threadIdx.x;
  if (i < 663552) {
    int r = (i / 192) % 576;
    float v = s[i];
    if (r < 192) v *= SCALE;
    d[i] = f2bf(v);
  }
}

// qkv bias scaled fp32 copy
__global__ __launch_bounds__(256) void scale_qkvb_k(const float* __restrict__ s,
                                                    float* __restrict__ d) {
  int i = (blockIdx.x << 8) + threadIdx.x;
  if (i < 3456) {
    float v = s[i];
    if ((i % 576) < 192) v *= SCALE;
    d[i] = v;
  }
}

// conv weights [192][192ci][3][3] -> tap-major bf16 [192][9 tap][192 ci]
__global__ __launch_bounds__(256) void cvt_conv_k(const float* __restrict__ s,
                                                  unsigned short* __restrict__ d) {
  int i = (blockIdx.x << 8) + threadIdx.x;
  if (i < 331776) {
    int o = i / 1728;
    int r = i - o * 1728;
    int tap = r / 192;
    int ci = r - tap * 192;
    d[i] = f2bf(s[o * 1728 + ci * 9 + tap]);
  }
}

// ---------------- patch embed LN, coalesced via LDS transpose --------------
__global__ __launch_bounds__(256) void embed_ln_t_k(
    const float* __restrict__ x, const float* __restrict__ g,
    const float* __restrict__ be, float* __restrict__ y) {
  __shared__ float ts[192 * 65];
  const int w = threadIdx.x >> 6, lane = threadIdx.x & 63;
  const int t0 = blockIdx.x << 6;
  const int b = t0 >> 12, tb = t0 & 4095;
  const float* xb = x + (((size_t)b * DIM) << 12) + tb;
#pragma unroll
  for (int j = 0; j < 48; ++j) {
    int ch = w * 48 + j;
    ts[ch * 65 + lane] = xb[((size_t)ch << 12) + lane];
  }
  __syncthreads();
#pragma unroll 4
  for (int idx = 0; idx < 16; ++idx) {
    int tk = (w << 4) + idx;
    float v0 = ts[lane * 65 + tk];
    float v1 = ts[(lane + 64) * 65 + tk];
    float v2 = ts[(lane + 128) * 65 + tk];
    float mu = waveSum(v0 + v1 + v2) * (1.f / 192.f);
    float d0 = v0 - mu, d1 = v1 - mu, d2 = v2 - mu;
    float var = waveSum(d0 * d0 + d1 * d1 + d2 * d2) * (1.f / 192.f);
    float rs = rsqrtf(var + 1e-5f);
    float* yp = y + (size_t)(t0 + tk) * DIM;
    yp[lane] = d0 * rs * g[lane] + be[lane];
    yp[lane + 64] = d1 * rs * g[lane + 64] + be[lane + 64];
    yp[lane + 128] = d2 * rs * g[lane + 128] + be[lane + 128];
  }
}

// ---------------- LN1 + window partition -> bf16 (block 0 only) ------------
__global__ __launch_bounds__(256) void ln_window_k(
    const float* __restrict__ y, const float* __restrict__ g,
    const float* __restrict__ be, unsigned short* __restrict__ xw,
    int shifted) {
  int m = (blockIdx.x << 2) + (threadIdx.x >> 6);
  int lane = threadIdx.x & 63;
  int widx = m >> 6, n = m & 63;
  int b = widx >> 6, win = widx & 63;
  int hp = ((win >> 3) << 3) + (n >> 3);
  int wp = ((win & 7) << 3) + (n & 7);
  if (shifted) { hp = (hp + 4) & 63; wp = (wp + 4) & 63; }
  int src = (b << 12) + (hp << 6) + wp;
  const float* yp = y + (size_t)src * DIM;
  float v0 = yp[lane], v1 = yp[lane + 64], v2 = yp[lane + 128];
  float mu = waveSum(v0 + v1 + v2) * (1.f / 192.f);
  float d0 = v0 - mu, d1 = v1 - mu, d2 = v2 - mu;
  float var = waveSum(d0 * d0 + d1 * d1 + d2 * d2) * (1.f / 192.f);
  float rs = rsqrtf(var + 1e-5f);
  unsigned short* op = xw + (size_t)m * DIM;
  op[lane] = f2bf(d0 * rs * g[lane] + be[lane]);
  op[lane + 64] = f2bf(d1 * rs * g[lane + 64] + be[lane + 64]);
  op[lane + 128] = f2bf(d2 * rs * g[lane + 128] + be[lane + 128]);
}

// ---------------- MFMA windowed attention: 1 wave per (window, head) -------
__global__ __launch_bounds__(64) void attn_k(
    const unsigned short* __restrict__ qkv, const float* __restrict__ rpb,
    unsigned short* __restrict__ out, int shifted, int widx0) {
  __shared__ unsigned short vt[32 * 72];
  __shared__ unsigned short pl[64 * 72];
  __shared__ float rp[228];
  const int lwidx = blockIdx.x / HEADS;
  const int head = blockIdx.x - lwidx * HEADS;
  const int l = threadIdx.x;
  const int g = l >> 4, li = l & 15;

  for (int i = l; i < 225; i += 64) rp[i] = rpb[i * HEADS + head];

  const unsigned short* base = qkv + (size_t)lwidx * 64 * QKV_D + head * HD;

  bf16x8 qf[4], kf[4];
#pragma unroll
  for (int n = 0; n < 4; ++n)
    qf[n] = *(const bf16x8*)(base + (size_t)(16 * n + li) * QKV_D + g * 8);
#pragma unroll
  for (int i = 0; i < 4; ++i)
    kf[i] = *(const bf16x8*)(base + (size_t)(16 * i + li) * QKV_D + DIM + g * 8);

#pragma unroll
  for (int p = 0; p < 4; ++p) {
    int r = 16 * p + (l >> 2);
    int d0 = (l & 3) << 3;
    bf16x8 v8 = *(const bf16x8*)(base + (size_t)r * QKV_D + 2 * DIM + d0);
#pragma unroll
    for (int e = 0; e < 8; ++e)
      vt[(d0 + e) * 72 + r] = ((const unsigned short*)&v8)[e];
  }

  f32x4 s[4][4] = {};
#pragma unroll
  for (int i = 0; i < 4; ++i)
#pragma unroll
    for (int n = 0; n < 4; ++n)
      s[i][n] = __builtin_amdgcn_mfma_f32_16x16x32_bf16(kf[i], qf[n], s[i][n],
                                                        0, 0, 0);
  __syncthreads();

  const int win = (widx0 + lwidx) & 63;
  const int wh = (win >> 3) << 3, wwp = (win & 7) << 3;
  int rq[4], cq[4], zq[4];
#pragma unroll
  for (int n = 0; n < 4; ++n) {
    int q = 16 * n + li;
    rq[n] = q >> 3;
    cq[n] = q & 7;
    zq[n] = 0;
    if (shifted) {
      int hq = wh + rq[n], wq = wwp + cq[n];
      int zr = hq < 56 ? 0 : (hq < 60 ? 1 : 2);
      int zc = wq < 56 ? 0 : (wq < 60 ? 1 : 2);
      zq[n] = 3 * zr + zc;
    }
  }
#pragma unroll
  for (int i = 0; i < 4; ++i)
#pragma unroll
    for (int j = 0; j < 4; ++j) {
      int m = 16 * i + 4 * g + j;
      int rm = m >> 3, cm = m & 7;
      int zm = 0;
      if (shifted) {
        int hm = wh + rm, wm = wwp + cm;
        int zr = hm < 56 ? 0 : (hm < 60 ? 1 : 2);
        int zc = wm < 56 ? 0 : (wm < 60 ? 1 : 2);
        zm = 3 * zr + zc;
      }
#pragma unroll
      for (int n = 0; n < 4; ++n) {
        float b = rp[(rq[n] - rm + 7) * 15 + (cq[n] - cm + 7)];
        if (shifted && zm != zq[n]) b -= 100.f;
        s[i][n][j] += b;
      }
    }

  float inv[4];
#pragma unroll
  for (int n = 0; n < 4; ++n) {
    float m0 = -1e30f;
#pragma unroll
    for (int i = 0; i < 4; ++i)
#pragma unroll
      for (int j = 0; j < 4; ++j) m0 = fmaxf(m0, s[i][n][j]);
    m0 = fmaxf(m0, __shfl_xor(m0, 16, 64));
    m0 = fmaxf(m0, __shfl_xor(m0, 32, 64));
    float s0 = 0.f;
#pragma unroll
    for (int i = 0; i < 4; ++i)
#pragma unroll
      for (int j = 0; j < 4; ++j) {
        float e = __expf(s[i][n][j] - m0);
        s[i][n][j] = e;
        s0 += e;
      }
    s0 += __shfl_xor(s0, 16, 64);
    s0 += __shfl_xor(s0, 32, 64);
    inv[n] = 1.f / s0;
  }

#pragma unroll
  for (int n = 0; n < 4; ++n) {
    int q = 16 * n + li;
#pragma unroll
    for (int i = 0; i < 4; ++i) {
      unsigned lo = (unsigned)f2bf(s[i][n][0]) | ((unsigned)f2bf(s[i][n][1]) << 16);
      unsigned hi = (unsigned)f2bf(s[i][n][2]) | ((unsigned)f2bf(s[i][n][3]) << 16);
      *(uint2*)&pl[q * 72 + 16 * i + 4 * g] = uint2{lo, hi};
    }
  }
  __syncthreads();

  f32x4 o[2][4] = {};
#pragma unroll
  for (int ks = 0; ks < 2; ++ks) {
    bf16x8 va[2], pb[4];
#pragma unroll
    for (int i2 = 0; i2 < 2; ++i2)
      va[i2] = *(const bf16x8*)&vt[(16 * i2 + li) * 72 + 32 * ks + 8 * g];
#pragma unroll
    for (int n2 = 0; n2 < 4; ++n2)
      pb[n2] = *(const bf16x8*)&pl[(16 * n2 + li) * 72 + 32 * ks + 8 * g];
#pragma unroll
    for (int i2 = 0; i2 < 2; ++i2)
#pragma unroll
      for (int n2 = 0; n2 < 4; ++n2)
        o[i2][n2] = __builtin_amdgcn_mfma_f32_16x16x32_bf16(va[i2], pb[n2],
                                                            o[i2][n2], 0, 0, 0);
  }

  unsigned short* ob = out + (size_t)(lwidx * 64) * DIM + head * HD;
#pragma unroll
  for (int i2 = 0; i2 < 2; ++i2)
#pragma unroll
    for (int n2 = 0; n2 < 4; ++n2) {
      int q = 16 * n2 + li;
      float iv = inv[n2];
      unsigned lo = (unsigned)f2bf(o[i2][n2][0] * iv) |
                    ((unsigned)f2bf(o[i2][n2][1] * iv) << 16);
      unsigned hi = (unsigned)f2bf(o[i2][n2][2] * iv) |
                    ((unsigned)f2bf(o[i2][n2][3] * iv) << 16);
      *(uint2*)(ob + (size_t)q * DIM + 16 * i2 + 4 * g) = uint2{lo, hi};
    }
}

// ---------------- MFMA inner block (256x64 tile, BK=64, 4 waves x 64x64) ---
__device__ __forceinline__ void mfma_block256(const unsigned short* As,
                                              const unsigned short* Bs,
                                              f32x4 acc[4][4], int w,
                                              int lane) {
  const int frow = lane & 15;
  const int fk = (lane >> 4) << 3;
#pragma unroll
  for (int kk = 0; kk < 64; kk += 32) {
    int slotk = (kk + fk) >> 3;
    bf16x8 a[4], b[4];
#pragma unroll
    for (int m = 0; m < 4; ++m) {
      int ar = (w << 6) + (m << 4) + frow;
      a[m] = *(const bf16x8*)&As[(ar << 6) + ((slotk ^ (ar & 7)) << 3)];
    }
#pragma unroll
    for (int n = 0; n < 4; ++n) {
      int br = (n << 4) + frow;
      b[n] = *(const bf16x8*)&Bs[(br << 6) + ((slotk ^ (br & 7)) << 3)];
    }
#pragma unroll
    for (int m = 0; m < 4; ++m)
#pragma unroll
      for (int n = 0; n < 4; ++n)
        acc[m][n] =
            __builtin_amdgcn_mfma_f32_16x16x32_bf16(a[m], b[n], acc[m][n], 0,
                                                    0, 0);
  }
}

// ---------------- MFMA inner block (128x64 tile, 4 waves x 32x64) ----------
__device__ __forceinline__ void mfma_block128(const unsigned short* As,
                                              const unsigned short* Bs,
                                              f32x4 acc[2][4], int w,
                                              int lane) {
  const int frow = lane & 15;
  const int fk = (lane >> 4) << 3;
#pragma unroll
  for (int kk = 0; kk < 64; kk += 32) {
    int slotk = (kk + fk) >> 3;
    int ar0 = (w << 5) + frow, ar1 = ar0 + 16;
    bf16x8 a0 = *(const bf16x8*)&As[(ar0 << 6) + ((slotk ^ (ar0 & 7)) << 3)];
    bf16x8 a1 = *(const bf16x8*)&As[(ar1 << 6) + ((slotk ^ (ar1 & 7)) << 3)];
    bf16x8 b[4];
#pragma unroll
    for (int n = 0; n < 4; ++n) {
      int br = (n << 4) + frow;
      b[n] = *(const bf16x8*)&Bs[(br << 6) + ((slotk ^ (br & 7)) << 3)];
    }
#pragma unroll
    for (int n = 0; n < 4; ++n) {
      acc[0][n] = __builtin_amdgcn_mfma_f32_16x16x32_bf16(a0, b[n], acc[0][n], 0, 0, 0);
      acc[1][n] = __builtin_amdgcn_mfma_f32_16x16x32_bf16(a1, b[n], acc[1][n], 0, 0, 0);
    }
  }
}

// ---------------- MFMA bf16 GEMM (N-tiled): bf16 out (QKV) -----------------
template <int EPI>
__global__ __launch_bounds__(256) void mgemm_k(
    const unsigned short* __restrict__ A, const unsigned short* __restrict__ W,
    const float* __restrict__ bias, void* __restrict__ Cv, int N, int K) {
  __shared__ unsigned short As[256 * 64];
  __shared__ unsigned short Bs[64 * 64];
  const int tid = threadIdx.x;
  const int w = tid >> 6, lane = tid & 63;
  const int row0 = blockIdx.x << 8;
  const int col0 = blockIdx.y << 6;
  f32x4 acc[4][4] = {};

  for (int k0 = 0; k0 < K; k0 += 64) {
    if (k0) __syncthreads();
#pragma unroll
    for (int r = 0; r < 2; ++r) {
      int q = (r << 8) + tid;
      int brow = q >> 3, cs = q & 7;
      int kg = cs ^ (brow & 7);
      GLD(W + (size_t)(col0 + brow) * K + k0 + (kg << 3),
          Bs + (((r << 8) + (w << 6)) << 3));
    }
#pragma unroll
    for (int r = 0; r < 8; ++r) {
      int q = (r << 8) + tid;
      int arow = q >> 3, cs = q & 7;
      int kg = cs ^ (arow & 7);
      GLD(A + (size_t)(row0 + arow) * K + k0 + (kg << 3),
          As + (((r << 8) + (w << 6)) << 3));
    }
    __syncthreads();
    mfma_block256(As, Bs, acc, w, lane);
  }

  const int erow = (lane >> 4) << 2;
  const int ecol = lane & 15;
#pragma unroll
  for (int mr = 0; mr < 4; ++mr)
#pragma unroll
    for (int nr = 0; nr < 4; ++nr)
#pragma unroll
      for (int j = 0; j < 4; ++j) {
        int row = row0 + (w << 6) + (mr << 4) + erow + j;
        int col = col0 + (nr << 4) + ecol;
        float v = acc[mr][nr][j];
        ((unsigned short*)Cv)[(size_t)row * N + col] = f2bf(v + bias[col]);
      }
}

// ---------------- fused proj + LN2 + MLP + LN1next (pm_k) ------------------
// Block = 64 window-rows. Proj with A-frags in registers; y-residual + LN2
// in-register; LN2 -> a2 LDS (wave-local) -> ap regs; MLP with dual W bufs.
// LAST=0: y = residual (fp32), LN1(next parity) -> lnout window row.
// LAST=1: final LN fused: y = LN(residual) fp32, lnout[tok] = bf16 LN.
template <int LAST>
__global__ __launch_bounds__(256) void pm_k(
    const unsigned short* __restrict__ A, const unsigned short* __restrict__ Wp,
    const float* __restrict__ bp, const float* __restrict__ g2,
    const float* __restrict__ be2, const unsigned short* __restrict__ W1,
    const float* __restrict__ b1, const unsigned short* __restrict__ W2,
    const float* __restrict__ b2, float* __restrict__ y,
    unsigned short* __restrict__ lnout, const float* __restrict__ g1,
    const float* __restrict__ be1, int sh_cur, int sh_next) {
  __shared__ unsigned short a2[64 * 192];   // ln2 rows, 3x[64][64] swizzled
  __shared__ unsigned short Wb1[64 * 192];  // W1 slice (3x[64][64])
  __shared__ unsigned short Wb2[192 * 64];  // Wp k0-slice / W2 slice [192][64]
  __shared__ unsigned short hc[64 * 64];
  const int tid = threadIdx.x;
  const int w = tid >> 6, lane = tid & 63;
  const int row0 = blockIdx.x << 6;
  const int frow = lane & 15;
  const int fk = (lane >> 4) << 3;
  const int erow = (lane >> 4) << 2;
  const int ecol = lane & 15;

  // A fragments in registers (wave rows (w<<4)+frow, 6 k-frags of 8)
  bf16x8 ap[6];
  {
    const unsigned short* arp = A + (size_t)(row0 + (w << 4) + frow) * 192 + fk;
#pragma unroll
    for (int t = 0; t < 6; ++t) ap[t] = *(const bf16x8*)(arp + t * 32);
  }

  // ---- proj: accp = A @ Wp^T ----
  f32x4 accp[12] = {};
#pragma unroll
  for (int k0 = 0; k0 < 192; k0 += 64) {
    __syncthreads();
#pragma unroll
    for (int r = 0; r < 6; ++r) {
      int q = (r << 8) + tid;
      int rw = q >> 3, cs = q & 7;
      int kg = cs ^ (rw & 7);
      GLD(Wp + (size_t)rw * 192 + k0 + (kg << 3),
          Wb2 + (((r << 8) + (w << 6)) << 3));
    }
    __syncthreads();
#pragma unroll
    for (int kk2 = 0; kk2 < 64; kk2 += 32) {
      int slotk = (kk2 + fk) >> 3;
      int t = (k0 + kk2) >> 5;
#pragma unroll
      for (int n = 0; n < 12; ++n) {
        int br = (n << 4) + frow;
        bf16x8 b = *(const bf16x8*)&Wb2[(br << 6) + ((slotk ^ (br & 7)) << 3)];
        accp[n] =
            __builtin_amdgcn_mfma_f32_16x16x32_bf16(ap[t], b, accp[n], 0, 0, 0);
      }
    }
  }

  // ---- y-residual + LN2 -> a2 (wave-local rows; vp kept in accp) ----
  int tokj[4];
  {
    float bpv[12], gv2[12], bv2[12];
#pragma unroll
    for (int n = 0; n < 12; ++n) {
      int col = (n << 4) + ecol;
      bpv[n] = bp[col];
      gv2[n] = g2[col];
      bv2[n] = be2[col];
    }
#pragma unroll
    for (int j = 0; j < 4; ++j) {
      int m = row0 + (w << 4) + erow + j;
      int n64 = m & 63, widx = m >> 6;
      int bl = widx >> 6, win = widx & 63;
      int hp = ((win >> 3) << 3) + (n64 >> 3);
      int wp2 = ((win & 7) << 3) + (n64 & 7);
      if (sh_cur) { hp = (hp + 4) & 63; wp2 = (wp2 + 4) & 63; }
      int tok = (bl << 12) + (hp << 6) + wp2;
      tokj[j] = tok;
      const float* yp = y + (size_t)tok * DIM;
      float s0 = 0.f;
#pragma unroll
      for (int n = 0; n < 12; ++n) {
        float v = accp[n][j] + bpv[n] + yp[(n << 4) + ecol];
        accp[n][j] = v;
        s0 += v;
      }
      float mu = rowSum16(s0) * (1.f / 192.f);
      float s1 = 0.f;
#pragma unroll
      for (int n = 0; n < 12; ++n) {
        float d = accp[n][j] - mu;
        s1 += d * d;
      }
      float rs = rsqrtf(rowSum16(s1) * (1.f / 192.f) + 1e-5f);
      int hr = (w << 4) + erow + j;
#pragma unroll
      for (int n = 0; n < 12; ++n) {
        int col = (n << 4) + ecol;
        unsigned short lv = f2bf((accp[n][j] - mu) * rs * gv2[n] + bv2[n]);
        int kb = col >> 6, c64 = col & 63;
        a2[(kb << 12) + (hr << 6) + (((c64 >> 3) ^ (hr & 7)) << 3) + (c64 & 7)] =
            lv;
      }
    }
  }
  // reload ap from a2 (wave-local rows; in-wave LDS ordering suffices)
  {
    int ar = (w << 4) + frow;
#pragma unroll
    for (int t = 0; t < 6; ++t) {
      int kb = t >> 1;
      int slotk = (((t & 1) << 5) + fk) >> 3;
      ap[t] = *(const bf16x8*)&a2[(kb << 12) + (ar << 6) +
                                  ((slotk ^ (ar & 7)) << 3)];
    }
  }

  // ---- MLP: acc2 = fc2(gelu(fc1(ln2))) ----
  f32x4 acc2[12] = {};
  for (int n0 = 0; n0 < 12; ++n0) {
    __syncthreads();  // Wb1/Wb2 free from previous gemms
#pragma unroll
    for (int r = 0; r < 6; ++r) {
      int q = (r << 8) + tid;
      int kb = q >> 9, rw = (q >> 3) & 63, cs = q & 7;
      int kg = cs ^ (rw & 7);
      GLD(W1 + (size_t)(n0 * 64 + rw) * 192 + kb * 64 + (kg << 3),
          Wb1 + (((r << 8) + (w << 6)) << 3));
    }
#pragma unroll
    for (int r = 0; r < 6; ++r) {
      int q = (r << 8) + tid;
      int rw = q >> 3, cs = q & 7;
      int kg = cs ^ (rw & 7);
      GLD(W2 + (size_t)rw * 768 + n0 * 64 + (kg << 3),
          Wb2 + (((r << 8) + (w << 6)) << 3));
    }
    __syncthreads();
    f32x4 acc1[4] = {};
#pragma unroll
    for (int kk = 0; kk < 192; kk += 32) {
      int kb = kk >> 6;
      int slotk = ((kk & 63) + fk) >> 3;
#pragma unroll
      for (int n = 0; n < 4; ++n) {
        int br = (n << 4) + frow;
        bf16x8 b = *(const bf16x8*)&Wb1[(kb << 12) + (br << 6) +
                                        ((slotk ^ (br & 7)) << 3)];
        acc1[n] = __builtin_amdgcn_mfma_f32_16x16x32_bf16(ap[kk >> 5], b,
                                                          acc1[n], 0, 0, 0);
      }
    }
    // tanh-form GELU -> hc (wave-local rows)
#pragma unroll
    for (int n = 0; n < 4; ++n) {
      float bb = b1[n0 * 64 + (n << 4) + ecol];
#pragma unroll
      for (int j = 0; j < 4; ++j) {
        int hr = (w << 4) + erow + j;
        int hcol = (n << 4) + ecol;
        float xg = acc1[n][j] + bb;
        float x3 = xg * xg * xg;
        float t1 = fmaf(0.044715f, x3, xg);
        float e = __expf(t1 * -1.5957691216057308f);
        float hv = xg * __builtin_amdgcn_rcpf(1.f + e);
        hc[(hr << 6) + (((hcol >> 3) ^ (hr & 7)) << 3) + (hcol & 7)] = f2bf(hv);
      }
    }
#pragma unroll
    for (int kk = 0; kk < 64; kk += 32) {
      int slotk = (kk + fk) >> 3;
      int ar = (w << 4) + frow;
      bf16x8 a = *(const bf16x8*)&hc[(ar << 6) + ((slotk ^ (ar & 7)) << 3)];
#pragma unroll
      for (int n = 0; n < 12; ++n) {
        int br = (n << 4) + frow;
        bf16x8 b = *(const bf16x8*)&Wb2[(br << 6) + ((slotk ^ (br & 7)) << 3)];
        acc2[n] =
            __builtin_amdgcn_mfma_f32_16x16x32_bf16(a, b, acc2[n], 0, 0, 0);
      }
    }
  }

  // ---- final: v = vp + fc2 + b2; LAST=0: y=v + LN1next scatter;
  //      LAST=1: y = LN(v) fp32 + token-ordered bf16 ----
  float b2v[12], gv[12], bev[12];
#pragma unroll
  for (int n = 0; n < 12; ++n) {
    int col = (n << 4) + ecol;
    b2v[n] = b2[col];
    gv[n] = g1[col];
    bev[n] = be1[col];
  }
#pragma unroll
  for (int j = 0; j < 4; ++j) {
    int tok = tokj[j];
    float* yp = y + (size_t)tok * DIM;
    float v[12];
    float s0 = 0.f;
#pragma unroll
    for (int n = 0; n < 12; ++n) {
      v[n] = accp[n][j] + acc2[n][j] + b2v[n];
      s0 += v[n];
    }
    float mu = rowSum16(s0) * (1.f / 192.f);
    float s1 = 0.f;
#pragma unroll
    for (int n = 0; n < 12; ++n) {
      float d = v[n] - mu;
      s1 += d * d;
    }
    float rs = rsqrtf(rowSum16(s1) * (1.f / 192.f) + 1e-5f);
    if (LAST == 0) {
#pragma unroll
      for (int n = 0; n < 12; ++n) yp[(n << 4) + ecol] = v[n];
      int hw = tok & 4095, gi = tok >> 12;
      int h = hw >> 6, ww2 = hw & 63;
      int hs = sh_next ? (h + 60) & 63 : h;
      int ws = sh_next ? (ww2 + 60) & 63 : ww2;
      int win = ((hs >> 3) << 3) | (ws >> 3);
      int n64 = ((hs & 7) << 3) | (ws & 7);
      size_t drow = ((size_t)gi << 12) + (win << 6) + n64;
      unsigned short* op = lnout + drow * DIM;
#pragma unroll
      for (int n = 0; n < 12; ++n)
        op[(n << 4) + ecol] = f2bf((v[n] - mu) * rs * gv[n] + bev[n]);
    } else {
      unsigned short* op = lnout + (size_t)tok * DIM;
#pragma unroll
      for (int n = 0; n < 12; ++n) {
        float r = (v[n] - mu) * rs * gv[n] + bev[n];
        yp[(n << 4) + ecol] = r;
        op[(n << 4) + ecol] = f2bf(r);
      }
    }
  }
}

// ---------------- conv 3x3 as 9 shifted tap-GEMMs + residual ---------------
__global__ __launch_bounds__(256) void conv_k(
    const unsigned short* __restrict__ A, const unsigned short* __restrict__ W,
    float* __restrict__ out, const float* __restrict__ Z,
    const unsigned short* __restrict__ zpg) {
  __shared__ unsigned short As[128 * 64];
  __shared__ unsigned short Bs[64 * 64];
  const int tid = threadIdx.x;
  const int w = tid >> 6, lane = tid & 63;
  const int row0 = blockIdx.x << 7;
  const int col0 = blockIdx.y << 6;
  f32x4 acc[2][4] = {};
  bool first = true;

#pragma unroll
  for (int tap = 0; tap < 9; ++tap) {
    const int dh = tap / 3 - 1, dw = tap % 3 - 1;
#pragma unroll
    for (int k0 = 0; k0 < 192; k0 += 64) {
      if (!first) __syncthreads();
      first = false;
#pragma unroll
      for (int r = 0; r < 2; ++r) {
        int q = (r << 8) + tid;
        int brow = q >> 3, cs = q & 7;
        int kg = cs ^ (brow & 7);
        GLD(W + (size_t)(col0 + brow) * 1728 + tap * 192 + k0 + (kg << 3),
            Bs + (((r << 8) + (w << 6)) << 3));
      }
#pragma unroll
      for (int r = 0; r < 4; ++r) {
        int q = (r << 8) + tid;
        int arow = q >> 3, cs = q & 7;
        int kg = cs ^ (arow & 7);
        int m = row0 + arow;
        int hw_ = m & 4095;
        int h = hw_ >> 6, ww = hw_ & 63;
        int ih = h + dh, iw = ww + dw;
        const unsigned short* src =
            ((unsigned)ih < 64u && (unsigned)iw < 64u)
                ? A + (size_t)(m + dh * 64 + dw) * DIM + k0 + (kg << 3)
                : zpg;
        GLD(src, As + (((r << 8) + (w << 6)) << 3));
      }
      __syncthreads();
      mfma_block128(As, Bs, acc, w, lane);
    }
  }

  const int erow = (lane >> 4) << 2;
  const int ecol = lane & 15;
#pragma unroll
  for (int mr = 0; mr < 2; ++mr)
#pragma unroll
    for (int nr = 0; nr < 4; ++nr)
#pragma unroll
      for (int j = 0; j < 4; ++j) {
        int row = row0 + (w << 5) + (mr << 4) + erow + j;  // global token
        int col = col0 + (nr << 4) + ecol;
        int b = row >> 12, hw_ = row & 4095;
        out[(((size_t)(b * DIM + col)) << 12) + hw_] =
            acc[mr][nr][j] + Z[(size_t)row * DIM + col];
      }
}

// ---------------------------------------------------------------------------
extern "C" void kernel_launch(void* const* d_in, const int* in_sizes, int n_in,
                              void* d_out, int out_size, void* d_ws,
                              size_t ws_size, hipStream_t stream) {
  const float* x = (const float*)d_in[0];
  const float* en_g = (const float*)d_in[1];
  const float* en_b = (const float*)d_in[2];
  const float* n1_g = (const float*)d_in[3];
  const float* n1_b = (const float*)d_in[4];
  const float* qkv_w = (const float*)d_in[5];
  const float* qkv_b = (const float*)d_in[6];
  const float* proj_w = (const float*)d_in[7];
  const float* proj_b = (const float*)d_in[8];
  const float* rpb = (const float*)d_in[9];
  const float* n2_g = (const float*)d_in[10];
  const float* n2_b = (const float*)d_in[11];
  const float* fc1_w = (const float*)d_in[12];
  const float* fc1_b = (const float*)d_in[13];
  const float* fc2_w = (const float*)d_in[14];
  const float* fc2_b = (const float*)d_in[15];
  const float* fn_g = (const float*)d_in[16];
  const float* fn_b = (const float*)d_in[17];
  const float* conv_w = (const float*)d_in[18];
  float* out = (float*)d_out;

  // workspace layout (bytes):
  //   y      @ 0          fp32 [65536,192]             50331648
  //   buf1a  @ 50331648   bf16 [65536,192]             25165824
  //   buf1b  @ 75497472   bf16 [65536,192]             25165824
  //   wbuf   @ 100663296  bf16 weights                  5971968
  //   zpg    @ 106635264  zero page                         256
  //   qkv_bs @ 106635520  scaled qkv bias fp32            13824  -> 106.65MB
  // qkv scratch = d_out (50.3MB >= 37.7MB needed; fully overwritten by
  // conv_k at the end of every call -> graph-safe).
  float* y = (float*)d_ws;
  unsigned short* buf1a = (unsigned short*)((char*)d_ws + 50331648);
  unsigned short* buf1b = (unsigned short*)((char*)d_ws + 75497472);
  unsigned short* wbuf = (unsigned short*)((char*)d_ws + 100663296);
  unsigned short* zpg = (unsigned short*)((char*)d_ws + 106635264);
  float* qkv_bs = (float*)((char*)d_ws + 106635520);
  unsigned short* qkvbuf = (unsigned short*)d_out;

  unsigned short* qkv_wb = wbuf;             // 6*576*192  = 663552
  unsigned short* proj_wb = wbuf + 663552;   // 6*192*192  = 221184
  unsigned short* fc1_wb = wbuf + 884736;    // 6*768*192  = 884736
  unsigned short* fc2_wb = wbuf + 1769472;   // 6*192*768  = 884736
  unsigned short* conv_wb = wbuf + 2654208;  // 192*1728   = 331776

  zero_k<<<1, 64, 0, stream>>>((float*)zpg);
  cvt_qkv_k<<<2592, 256, 0, stream>>>(qkv_w, qkv_wb);
  scale_qkvb_k<<<14, 256, 0, stream>>>(qkv_b, qkv_bs);
  cvt_k<<<216, 256, 0, stream>>>(proj_w, proj_wb, 221184);
  cvt_k<<<864, 256, 0, stream>>>(fc1_w, fc1_wb, 884736);
  cvt_k<<<864, 256, 0, stream>>>(fc2_w, fc2_wb, 884736);
  cvt_conv_k<<<1296, 256, 0, stream>>>(conv_w, conv_wb);

  embed_ln_t_k<<<1024, 256, 0, stream>>>(x, en_g, en_b, y);
  // block 0 LN1 + window partition (sh = 0) -> buf1a
  ln_window_k<<<16384, 256, 0, stream>>>(y, n1_g, n1_b, buf1a, 0);

  for (int i = 0; i < 6; ++i) {
    int sh = i & 1;
    unsigned short* bufA = (i & 1) ? buf1b : buf1a;
    unsigned short* bufB = (i & 1) ? buf1a : buf1b;
    // qkv + attention in 2 chunks (qkv scratch = d_out)
    for (int c = 0; c < 2; ++c) {
      unsigned short* bAc = bufA + (size_t)c * CHQ * DIM;
      mgemm_k<3><<<dim3(CHQ / 256, 9), 256, 0, stream>>>(
          bAc, qkv_wb + (size_t)i * QKV_D * DIM, qkv_bs + i * QKV_D, qkvbuf,
          QKV_D, DIM);
      attn_k<<<(CHQ / 64) * HEADS, 64, 0, stream>>>(
          qkvbuf, rpb + i * 225 * HEADS, bAc, sh, c * (CHQ / 64));
    }
    // fused proj + LN2 + MLP + LN1next (LAST: final LN fused)
    if (i < 5) {
      pm_k<0><<<TOK / 64, 256, 0, stream>>>(
          bufA, proj_wb + (size_t)i * DIM * DIM, proj_b + i * DIM,
          n2_g + i * DIM, n2_b + i * DIM, fc1_wb + (size_t)i * MLP_D * DIM,
          fc1_b + i * MLP_D, fc2_wb + (size_t)i * DIM * MLP_D, fc2_b + i * DIM,
          y, bufB, n1_g + (i + 1) * DIM, n1_b + (i + 1) * DIM, sh, (i + 1) & 1);
    } else {
      pm_k<1><<<TOK / 64, 256, 0, stream>>>(
          bufA, proj_wb + (size_t)i * DIM * DIM, proj_b + i * DIM,
          n2_g + i * DIM, n2_b + i * DIM, fc1_wb + (size_t)i * MLP_D * DIM,
          fc1_b + i * MLP_D, fc2_wb + (size_t)i * DIM * MLP_D, fc2_b + i * DIM,
          y, bufB, fn_g, fn_b, sh, 0);
    }
  }

  // tail: single conv dispatch (A = buf1a bf16 LN'd, Z = y fp32 LN'd)
  conv_k<<<dim3(TOK / 128, 3), 256, 0, stream>>>(buf1a, conv_wb, out, y, zpg);
}

// Round 21
// 1167.150 us; speedup vs baseline: 1.2651x; 1.2651x over previous
//
#include <hip/hip_runtime.h>
#include <cstdint>
#include <cstddef>

// Problem constants
#define BATCH 16
#define DIM 192
#define HEADS 6
#define HD 32
#define TOK 65536
#define QKV_D 576
#define MLP_D 768
#define SCALE 0.17677669529663687f  // 32^-0.5

#define CHQ 32768    // chunk for qkv+attention phase (8 images)

typedef __bf16 bf16x8 __attribute__((ext_vector_type(8)));
typedef float f32x4 __attribute__((ext_vector_type(4)));

__device__ __forceinline__ unsigned short f2bf(float f) {
  union { float f; unsigned u; } c;
  c.f = f;
  return (unsigned short)((c.u + 0x7fffu + ((c.u >> 16) & 1)) >> 16);
}

__device__ __forceinline__ float waveSum(float v) {
#pragma unroll
  for (int off = 32; off; off >>= 1) v += __shfl_xor(v, off, 64);
  return v;
}

// reduce across the 16 lanes sharing a C-row (lane>>4 fixed)
__device__ __forceinline__ float rowSum16(float v) {
  v += __shfl_xor(v, 1, 64);
  v += __shfl_xor(v, 2, 64);
  v += __shfl_xor(v, 4, 64);
  v += __shfl_xor(v, 8, 64);
  return v;
}

// global -> LDS direct (16B/lane). LDS dest wave-uniform base + lane*16.
#define GLD(SRC, DST)                                                     \
  __builtin_amdgcn_global_load_lds(                                       \
      (const __attribute__((address_space(1))) void*)(SRC),               \
      (__attribute__((address_space(3))) void*)(DST), 16, 0, 0)

// ---------------- small utility kernels ------------------------------------
__global__ __launch_bounds__(64) void zero_k(float* p) { p[threadIdx.x] = 0.f; }

__global__ __launch_bounds__(256) void cvt_k(const float* __restrict__ s,
                                             unsigned short* __restrict__ d,
                                             int n) {
  int i = ((blockIdx.x << 8) + threadIdx.x) << 2;
  if (i < n) {
    float4 v = *(const float4*)(s + i);
    d[i] = f2bf(v.x);
    d[i + 1] = f2bf(v.y);
    d[i + 2] = f2bf(v.z);
    d[i + 3] = f2bf(v.w);
  }
}

// qkv weights -> bf16 with Q rows (row%576 < 192) pre-scaled by SCALE
__global__ __launch_bounds__(256) void cvt_qkv_k(const float* __restrict__ s,
                                                 unsigned short* __restrict__ d) {
  int i = (blockIdx.x << 8) + threadIdx.x;
  if (i < 663552) {
    int r = (i / 192) % 576;
    float v = s[i];
    if (r < 192) v *= SCALE;
    d[i] = f2bf(v);
  }
}

// qkv bias scaled fp32 copy
__global__ __launch_bounds__(256) void scale_qkvb_k(const float* __restrict__ s,
                                                    float* __restrict__ d) {
  int i = (blockIdx.x << 8) + threadIdx.x;
  if (i < 3456) {
    float v = s[i];
    if ((i % 576) < 192) v *= SCALE;
    d[i] = v;
  }
}

// conv weights [192][192ci][3][3] -> tap-major bf16 [192][9 tap][192 ci]
__global__ __launch_bounds__(256) void cvt_conv_k(const float* __restrict__ s,
                                                  unsigned short* __restrict__ d) {
  int i = (blockIdx.x << 8) + threadIdx.x;
  if (i < 331776) {
    int o = i / 1728;
    int r = i - o * 1728;
    int tap = r / 192;
    int ci = r - tap * 192;
    d[i] = f2bf(s[o * 1728 + ci * 9 + tap]);
  }
}

// ---------------- patch embed LN, coalesced via LDS transpose --------------
__global__ __launch_bounds__(256) void embed_ln_t_k(
    const float* __restrict__ x, const float* __restrict__ g,
    const float* __restrict__ be, float* __restrict__ y) {
  __shared__ float ts[192 * 65];
  const int w = threadIdx.x >> 6, lane = threadIdx.x & 63;
  const int t0 = blockIdx.x << 6;
  const int b = t0 >> 12, tb = t0 & 4095;
  const float* xb = x + (((size_t)b * DIM) << 12) + tb;
#pragma unroll
  for (int j = 0; j < 48; ++j) {
    int ch = w * 48 + j;
    ts[ch * 65 + lane] = xb[((size_t)ch << 12) + lane];
  }
  __syncthreads();
#pragma unroll 4
  for (int idx = 0; idx < 16; ++idx) {
    int tk = (w << 4) + idx;
    float v0 = ts[lane * 65 + tk];
    float v1 = ts[(lane + 64) * 65 + tk];
    float v2 = ts[(lane + 128) * 65 + tk];
    float mu = waveSum(v0 + v1 + v2) * (1.f / 192.f);
    float d0 = v0 - mu, d1 = v1 - mu, d2 = v2 - mu;
    float var = waveSum(d0 * d0 + d1 * d1 + d2 * d2) * (1.f / 192.f);
    float rs = rsqrtf(var + 1e-5f);
    float* yp = y + (size_t)(t0 + tk) * DIM;
    yp[lane] = d0 * rs * g[lane] + be[lane];
    yp[lane + 64] = d1 * rs * g[lane + 64] + be[lane + 64];
    yp[lane + 128] = d2 * rs * g[lane + 128] + be[lane + 128];
  }
}

// ---------------- LN1 + window partition -> bf16 (block 0 only) ------------
__global__ __launch_bounds__(256) void ln_window_k(
    const float* __restrict__ y, const float* __restrict__ g,
    const float* __restrict__ be, unsigned short* __restrict__ xw,
    int shifted) {
  int m = (blockIdx.x << 2) + (threadIdx.x >> 6);
  int lane = threadIdx.x & 63;
  int widx = m >> 6, n = m & 63;
  int b = widx >> 6, win = widx & 63;
  int hp = ((win >> 3) << 3) + (n >> 3);
  int wp = ((win & 7) << 3) + (n & 7);
  if (shifted) { hp = (hp + 4) & 63; wp = (wp + 4) & 63; }
  int src = (b << 12) + (hp << 6) + wp;
  const float* yp = y + (size_t)src * DIM;
  float v0 = yp[lane], v1 = yp[lane + 64], v2 = yp[lane + 128];
  float mu = waveSum(v0 + v1 + v2) * (1.f / 192.f);
  float d0 = v0 - mu, d1 = v1 - mu, d2 = v2 - mu;
  float var = waveSum(d0 * d0 + d1 * d1 + d2 * d2) * (1.f / 192.f);
  float rs = rsqrtf(var + 1e-5f);
  unsigned short* op = xw + (size_t)m * DIM;
  op[lane] = f2bf(d0 * rs * g[lane] + be[lane]);
  op[lane + 64] = f2bf(d1 * rs * g[lane + 64] + be[lane + 64]);
  op[lane + 128] = f2bf(d2 * rs * g[lane + 128] + be[lane + 128]);
}

// ---------------- MFMA windowed attention: 1 wave per (window, head) -------
__global__ __launch_bounds__(64) void attn_k(
    const unsigned short* __restrict__ qkv, const float* __restrict__ rpb,
    unsigned short* __restrict__ out, int shifted, int widx0) {
  __shared__ unsigned short vt[32 * 72];
  __shared__ unsigned short pl[64 * 72];
  __shared__ float rp[228];
  const int lwidx = blockIdx.x / HEADS;
  const int head = blockIdx.x - lwidx * HEADS;
  const int l = threadIdx.x;
  const int g = l >> 4, li = l & 15;

  for (int i = l; i < 225; i += 64) rp[i] = rpb[i * HEADS + head];

  const unsigned short* base = qkv + (size_t)lwidx * 64 * QKV_D + head * HD;

  bf16x8 qf[4], kf[4];
#pragma unroll
  for (int n = 0; n < 4; ++n)
    qf[n] = *(const bf16x8*)(base + (size_t)(16 * n + li) * QKV_D + g * 8);
#pragma unroll
  for (int i = 0; i < 4; ++i)
    kf[i] = *(const bf16x8*)(base + (size_t)(16 * i + li) * QKV_D + DIM + g * 8);

#pragma unroll
  for (int p = 0; p < 4; ++p) {
    int r = 16 * p + (l >> 2);
    int d0 = (l & 3) << 3;
    bf16x8 v8 = *(const bf16x8*)(base + (size_t)r * QKV_D + 2 * DIM + d0);
#pragma unroll
    for (int e = 0; e < 8; ++e)
      vt[(d0 + e) * 72 + r] = ((const unsigned short*)&v8)[e];
  }

  f32x4 s[4][4] = {};
#pragma unroll
  for (int i = 0; i < 4; ++i)
#pragma unroll
    for (int n = 0; n < 4; ++n)
      s[i][n] = __builtin_amdgcn_mfma_f32_16x16x32_bf16(kf[i], qf[n], s[i][n],
                                                        0, 0, 0);
  __syncthreads();

  const int win = (widx0 + lwidx) & 63;
  const int wh = (win >> 3) << 3, wwp = (win & 7) << 3;
  int rq[4], cq[4], zq[4];
#pragma unroll
  for (int n = 0; n < 4; ++n) {
    int q = 16 * n + li;
    rq[n] = q >> 3;
    cq[n] = q & 7;
    zq[n] = 0;
    if (shifted) {
      int hq = wh + rq[n], wq = wwp + cq[n];
      int zr = hq < 56 ? 0 : (hq < 60 ? 1 : 2);
      int zc = wq < 56 ? 0 : (wq < 60 ? 1 : 2);
      zq[n] = 3 * zr + zc;
    }
  }
#pragma unroll
  for (int i = 0; i < 4; ++i)
#pragma unroll
    for (int j = 0; j < 4; ++j) {
      int m = 16 * i + 4 * g + j;
      int rm = m >> 3, cm = m & 7;
      int zm = 0;
      if (shifted) {
        int hm = wh + rm, wm = wwp + cm;
        int zr = hm < 56 ? 0 : (hm < 60 ? 1 : 2);
        int zc = wm < 56 ? 0 : (wm < 60 ? 1 : 2);
        zm = 3 * zr + zc;
      }
#pragma unroll
      for (int n = 0; n < 4; ++n) {
        float b = rp[(rq[n] - rm + 7) * 15 + (cq[n] - cm + 7)];
        if (shifted && zm != zq[n]) b -= 100.f;
        s[i][n][j] += b;
      }
    }

  float inv[4];
#pragma unroll
  for (int n = 0; n < 4; ++n) {
    float m0 = -1e30f;
#pragma unroll
    for (int i = 0; i < 4; ++i)
#pragma unroll
      for (int j = 0; j < 4; ++j) m0 = fmaxf(m0, s[i][n][j]);
    m0 = fmaxf(m0, __shfl_xor(m0, 16, 64));
    m0 = fmaxf(m0, __shfl_xor(m0, 32, 64));
    float s0 = 0.f;
#pragma unroll
    for (int i = 0; i < 4; ++i)
#pragma unroll
      for (int j = 0; j < 4; ++j) {
        float e = __expf(s[i][n][j] - m0);
        s[i][n][j] = e;
        s0 += e;
      }
    s0 += __shfl_xor(s0, 16, 64);
    s0 += __shfl_xor(s0, 32, 64);
    inv[n] = 1.f / s0;
  }

#pragma unroll
  for (int n = 0; n < 4; ++n) {
    int q = 16 * n + li;
#pragma unroll
    for (int i = 0; i < 4; ++i) {
      unsigned lo = (unsigned)f2bf(s[i][n][0]) | ((unsigned)f2bf(s[i][n][1]) << 16);
      unsigned hi = (unsigned)f2bf(s[i][n][2]) | ((unsigned)f2bf(s[i][n][3]) << 16);
      *(uint2*)&pl[q * 72 + 16 * i + 4 * g] = uint2{lo, hi};
    }
  }
  __syncthreads();

  f32x4 o[2][4] = {};
#pragma unroll
  for (int ks = 0; ks < 2; ++ks) {
    bf16x8 va[2], pb[4];
#pragma unroll
    for (int i2 = 0; i2 < 2; ++i2)
      va[i2] = *(const bf16x8*)&vt[(16 * i2 + li) * 72 + 32 * ks + 8 * g];
#pragma unroll
    for (int n2 = 0; n2 < 4; ++n2)
      pb[n2] = *(const bf16x8*)&pl[(16 * n2 + li) * 72 + 32 * ks + 8 * g];
#pragma unroll
    for (int i2 = 0; i2 < 2; ++i2)
#pragma unroll
      for (int n2 = 0; n2 < 4; ++n2)
        o[i2][n2] = __builtin_amdgcn_mfma_f32_16x16x32_bf16(va[i2], pb[n2],
                                                            o[i2][n2], 0, 0, 0);
  }

  unsigned short* ob = out + (size_t)(lwidx * 64) * DIM + head * HD;
#pragma unroll
  for (int i2 = 0; i2 < 2; ++i2)
#pragma unroll
    for (int n2 = 0; n2 < 4; ++n2) {
      int q = 16 * n2 + li;
      float iv = inv[n2];
      unsigned lo = (unsigned)f2bf(o[i2][n2][0] * iv) |
                    ((unsigned)f2bf(o[i2][n2][1] * iv) << 16);
      unsigned hi = (unsigned)f2bf(o[i2][n2][2] * iv) |
                    ((unsigned)f2bf(o[i2][n2][3] * iv) << 16);
      *(uint2*)(ob + (size_t)q * DIM + 16 * i2 + 4 * g) = uint2{lo, hi};
    }
}

// ---------------- MFMA inner block (256x64 tile, BK=64, 4 waves x 64x64) ---
__device__ __forceinline__ void mfma_block256(const unsigned short* As,
                                              const unsigned short* Bs,
                                              f32x4 acc[4][4], int w,
                                              int lane) {
  const int frow = lane & 15;
  const int fk = (lane >> 4) << 3;
#pragma unroll
  for (int kk = 0; kk < 64; kk += 32) {
    int slotk = (kk + fk) >> 3;
    bf16x8 a[4], b[4];
#pragma unroll
    for (int m = 0; m < 4; ++m) {
      int ar = (w << 6) + (m << 4) + frow;
      a[m] = *(const bf16x8*)&As[(ar << 6) + ((slotk ^ (ar & 7)) << 3)];
    }
#pragma unroll
    for (int n = 0; n < 4; ++n) {
      int br = (n << 4) + frow;
      b[n] = *(const bf16x8*)&Bs[(br << 6) + ((slotk ^ (br & 7)) << 3)];
    }
#pragma unroll
    for (int m = 0; m < 4; ++m)
#pragma unroll
      for (int n = 0; n < 4; ++n)
        acc[m][n] =
            __builtin_amdgcn_mfma_f32_16x16x32_bf16(a[m], b[n], acc[m][n], 0,
                                                    0, 0);
  }
}

// ---------------- MFMA inner block (128x64 tile, 4 waves x 32x64) ----------
__device__ __forceinline__ void mfma_block128(const unsigned short* As,
                                              const unsigned short* Bs,
                                              f32x4 acc[2][4], int w,
                                              int lane) {
  const int frow = lane & 15;
  const int fk = (lane >> 4) << 3;
#pragma unroll
  for (int kk = 0; kk < 64; kk += 32) {
    int slotk = (kk + fk) >> 3;
    int ar0 = (w << 5) + frow, ar1 = ar0 + 16;
    bf16x8 a0 = *(const bf16x8*)&As[(ar0 << 6) + ((slotk ^ (ar0 & 7)) << 3)];
    bf16x8 a1 = *(const bf16x8*)&As[(ar1 << 6) + ((slotk ^ (ar1 & 7)) << 3)];
    bf16x8 b[4];
#pragma unroll
    for (int n = 0; n < 4; ++n) {
      int br = (n << 4) + frow;
      b[n] = *(const bf16x8*)&Bs[(br << 6) + ((slotk ^ (br & 7)) << 3)];
    }
#pragma unroll
    for (int n = 0; n < 4; ++n) {
      acc[0][n] = __builtin_amdgcn_mfma_f32_16x16x32_bf16(a0, b[n], acc[0][n], 0, 0, 0);
      acc[1][n] = __builtin_amdgcn_mfma_f32_16x16x32_bf16(a1, b[n], acc[1][n], 0, 0, 0);
    }
  }
}

// ---------------- MFMA bf16 GEMM (N-tiled): bf16 out (QKV) -----------------
template <int EPI>
__global__ __launch_bounds__(256) void mgemm_k(
    const unsigned short* __restrict__ A, const unsigned short* __restrict__ W,
    const float* __restrict__ bias, void* __restrict__ Cv, int N, int K) {
  __shared__ unsigned short As[256 * 64];
  __shared__ unsigned short Bs[64 * 64];
  const int tid = threadIdx.x;
  const int w = tid >> 6, lane = tid & 63;
  const int row0 = blockIdx.x << 8;
  const int col0 = blockIdx.y << 6;
  f32x4 acc[4][4] = {};

  for (int k0 = 0; k0 < K; k0 += 64) {
    if (k0) __syncthreads();
#pragma unroll
    for (int r = 0; r < 2; ++r) {
      int q = (r << 8) + tid;
      int brow = q >> 3, cs = q & 7;
      int kg = cs ^ (brow & 7);
      GLD(W + (size_t)(col0 + brow) * K + k0 + (kg << 3),
          Bs + (((r << 8) + (w << 6)) << 3));
    }
#pragma unroll
    for (int r = 0; r < 8; ++r) {
      int q = (r << 8) + tid;
      int arow = q >> 3, cs = q & 7;
      int kg = cs ^ (arow & 7);
      GLD(A + (size_t)(row0 + arow) * K + k0 + (kg << 3),
          As + (((r << 8) + (w << 6)) << 3));
    }
    __syncthreads();
    mfma_block256(As, Bs, acc, w, lane);
  }

  const int erow = (lane >> 4) << 2;
  const int ecol = lane & 15;
#pragma unroll
  for (int mr = 0; mr < 4; ++mr)
#pragma unroll
    for (int nr = 0; nr < 4; ++nr)
#pragma unroll
      for (int j = 0; j < 4; ++j) {
        int row = row0 + (w << 6) + (mr << 4) + erow + j;
        int col = col0 + (nr << 4) + ecol;
        float v = acc[mr][nr][j];
        ((unsigned short*)Cv)[(size_t)row * N + col] = f2bf(v + bias[col]);
      }
}

// ---------------- fused proj + LN2 + MLP + LN1next (pm_k) ------------------
// Block = 64 window-rows. Proj with A-frags in registers; y-residual + LN2
// in-register; LN2 -> a2 LDS (wave-local) -> ap regs; MLP with dual W bufs.
// LAST=0: y = residual (fp32), LN1(next parity) -> lnout window row.
// LAST=1: final LN fused: y = LN(residual) fp32, lnout[tok] = bf16 LN.
template <int LAST>
__global__ __launch_bounds__(256) void pm_k(
    const unsigned short* __restrict__ A, const unsigned short* __restrict__ Wp,
    const float* __restrict__ bp, const float* __restrict__ g2,
    const float* __restrict__ be2, const unsigned short* __restrict__ W1,
    const float* __restrict__ b1, const unsigned short* __restrict__ W2,
    const float* __restrict__ b2, float* __restrict__ y,
    unsigned short* __restrict__ lnout, const float* __restrict__ g1,
    const float* __restrict__ be1, int sh_cur, int sh_next) {
  __shared__ unsigned short a2[64 * 192];   // ln2 rows, 3x[64][64] swizzled
  __shared__ unsigned short Wb1[64 * 192];  // W1 slice (3x[64][64])
  __shared__ unsigned short Wb2[192 * 64];  // Wp k0-slice / W2 slice [192][64]
  __shared__ unsigned short hc[64 * 64];
  const int tid = threadIdx.x;
  const int w = tid >> 6, lane = tid & 63;
  const int row0 = blockIdx.x << 6;
  const int frow = lane & 15;
  const int fk = (lane >> 4) << 3;
  const int erow = (lane >> 4) << 2;
  const int ecol = lane & 15;

  // A fragments in registers (wave rows (w<<4)+frow, 6 k-frags of 8)
  bf16x8 ap[6];
  {
    const unsigned short* arp = A + (size_t)(row0 + (w << 4) + frow) * 192 + fk;
#pragma unroll
    for (int t = 0; t < 6; ++t) ap[t] = *(const bf16x8*)(arp + t * 32);
  }

  // ---- proj: accp = A @ Wp^T ----
  f32x4 accp[12] = {};
#pragma unroll
  for (int k0 = 0; k0 < 192; k0 += 64) {
    __syncthreads();
#pragma unroll
    for (int r = 0; r < 6; ++r) {
      int q = (r << 8) + tid;
      int rw = q >> 3, cs = q & 7;
      int kg = cs ^ (rw & 7);
      GLD(Wp + (size_t)rw * 192 + k0 + (kg << 3),
          Wb2 + (((r << 8) + (w << 6)) << 3));
    }
    __syncthreads();
#pragma unroll
    for (int kk2 = 0; kk2 < 64; kk2 += 32) {
      int slotk = (kk2 + fk) >> 3;
      int t = (k0 + kk2) >> 5;
#pragma unroll
      for (int n = 0; n < 12; ++n) {
        int br = (n << 4) + frow;
        bf16x8 b = *(const bf16x8*)&Wb2[(br << 6) + ((slotk ^ (br & 7)) << 3)];
        accp[n] =
            __builtin_amdgcn_mfma_f32_16x16x32_bf16(ap[t], b, accp[n], 0, 0, 0);
      }
    }
  }

  // ---- y-residual + LN2 -> a2 (wave-local rows; vp kept in accp) ----
  int tokj[4];
  {
    float bpv[12], gv2[12], bv2[12];
#pragma unroll
    for (int n = 0; n < 12; ++n) {
      int col = (n << 4) + ecol;
      bpv[n] = bp[col];
      gv2[n] = g2[col];
      bv2[n] = be2[col];
    }
#pragma unroll
    for (int j = 0; j < 4; ++j) {
      int m = row0 + (w << 4) + erow + j;
      int n64 = m & 63, widx = m >> 6;
      int bl = widx >> 6, win = widx & 63;
      int hp = ((win >> 3) << 3) + (n64 >> 3);
      int wp2 = ((win & 7) << 3) + (n64 & 7);
      if (sh_cur) { hp = (hp + 4) & 63; wp2 = (wp2 + 4) & 63; }
      int tok = (bl << 12) + (hp << 6) + wp2;
      tokj[j] = tok;
      const float* yp = y + (size_t)tok * DIM;
      float s0 = 0.f;
#pragma unroll
      for (int n = 0; n < 12; ++n) {
        float v = accp[n][j] + bpv[n] + yp[(n << 4) + ecol];
        accp[n][j] = v;
        s0 += v;
      }
      float mu = rowSum16(s0) * (1.f / 192.f);
      float s1 = 0.f;
#pragma unroll
      for (int n = 0; n < 12; ++n) {
        float d = accp[n][j] - mu;
        s1 += d * d;
      }
      float rs = rsqrtf(rowSum16(s1) * (1.f / 192.f) + 1e-5f);
      int hr = (w << 4) + erow + j;
#pragma unroll
      for (int n = 0; n < 12; ++n) {
        int col = (n << 4) + ecol;
        unsigned short lv = f2bf((accp[n][j] - mu) * rs * gv2[n] + bv2[n]);
        int kb = col >> 6, c64 = col & 63;
        a2[(kb << 12) + (hr << 6) + (((c64 >> 3) ^ (hr & 7)) << 3) + (c64 & 7)] =
            lv;
      }
    }
  }
  // reload ap from a2 (wave-local rows; in-wave LDS ordering suffices)
  {
    int ar = (w << 4) + frow;
#pragma unroll
    for (int t = 0; t < 6; ++t) {
      int kb = t >> 1;
      int slotk = (((t & 1) << 5) + fk) >> 3;
      ap[t] = *(const bf16x8*)&a2[(kb << 12) + (ar << 6) +
                                  ((slotk ^ (ar & 7)) << 3)];
    }
  }

  // ---- MLP: acc2 = fc2(gelu(fc1(ln2))) ----
  f32x4 acc2[12] = {};
  for (int n0 = 0; n0 < 12; ++n0) {
    __syncthreads();  // Wb1/Wb2 free from previous gemms
#pragma unroll
    for (int r = 0; r < 6; ++r) {
      int q = (r << 8) + tid;
      int kb = q >> 9, rw = (q >> 3) & 63, cs = q & 7;
      int kg = cs ^ (rw & 7);
      GLD(W1 + (size_t)(n0 * 64 + rw) * 192 + kb * 64 + (kg << 3),
          Wb1 + (((r << 8) + (w << 6)) << 3));
    }
#pragma unroll
    for (int r = 0; r < 6; ++r) {
      int q = (r << 8) + tid;
      int rw = q >> 3, cs = q & 7;
      int kg = cs ^ (rw & 7);
      GLD(W2 + (size_t)rw * 768 + n0 * 64 + (kg << 3),
          Wb2 + (((r << 8) + (w << 6)) << 3));
    }
    __syncthreads();
    f32x4 acc1[4] = {};
#pragma unroll
    for (int kk = 0; kk < 192; kk += 32) {
      int kb = kk >> 6;
      int slotk = ((kk & 63) + fk) >> 3;
#pragma unroll
      for (int n = 0; n < 4; ++n) {
        int br = (n << 4) + frow;
        bf16x8 b = *(const bf16x8*)&Wb1[(kb << 12) + (br << 6) +
                                        ((slotk ^ (br & 7)) << 3)];
        acc1[n] = __builtin_amdgcn_mfma_f32_16x16x32_bf16(ap[kk >> 5], b,
                                                          acc1[n], 0, 0, 0);
      }
    }
    // tanh-form GELU -> hc (wave-local rows)
#pragma unroll
    for (int n = 0; n < 4; ++n) {
      float bb = b1[n0 * 64 + (n << 4) + ecol];
#pragma unroll
      for (int j = 0; j < 4; ++j) {
        int hr = (w << 4) + erow + j;
        int hcol = (n << 4) + ecol;
        float xg = acc1[n][j] + bb;
        float x3 = xg * xg * xg;
        float t1 = fmaf(0.044715f, x3, xg);
        float e = __expf(t1 * -1.5957691216057308f);
        float hv = xg * __builtin_amdgcn_rcpf(1.f + e);
        hc[(hr << 6) + (((hcol >> 3) ^ (hr & 7)) << 3) + (hcol & 7)] = f2bf(hv);
      }
    }
#pragma unroll
    for (int kk = 0; kk < 64; kk += 32) {
      int slotk = (kk + fk) >> 3;
      int ar = (w << 4) + frow;
      bf16x8 a = *(const bf16x8*)&hc[(ar << 6) + ((slotk ^ (ar & 7)) << 3)];
#pragma unroll
      for (int n = 0; n < 12; ++n) {
        int br = (n << 4) + frow;
        bf16x8 b = *(const bf16x8*)&Wb2[(br << 6) + ((slotk ^ (br & 7)) << 3)];
        acc2[n] =
            __builtin_amdgcn_mfma_f32_16x16x32_bf16(a, b, acc2[n], 0, 0, 0);
      }
    }
  }

  // ---- final: v = vp + fc2 + b2; LAST=0: y=v + LN1next scatter;
  //      LAST=1: y = LN(v) fp32 + token-ordered bf16 ----
  float b2v[12], gv[12], bev[12];
#pragma unroll
  for (int n = 0; n < 12; ++n) {
    int col = (n << 4) + ecol;
    b2v[n] = b2[col];
    gv[n] = g1[col];
    bev[n] = be1[col];
  }
#pragma unroll
  for (int j = 0; j < 4; ++j) {
    int tok = tokj[j];
    float* yp = y + (size_t)tok * DIM;
    float v[12];
    float s0 = 0.f;
#pragma unroll
    for (int n = 0; n < 12; ++n) {
      v[n] = accp[n][j] + acc2[n][j] + b2v[n];
      s0 += v[n];
    }
    float mu = rowSum16(s0) * (1.f / 192.f);
    float s1 = 0.f;
#pragma unroll
    for (int n = 0; n < 12; ++n) {
      float d = v[n] - mu;
      s1 += d * d;
    }
    float rs = rsqrtf(rowSum16(s1) * (1.f / 192.f) + 1e-5f);
    if (LAST == 0) {
#pragma unroll
      for (int n = 0; n < 12; ++n) yp[(n << 4) + ecol] = v[n];
      int hw = tok & 4095, gi = tok >> 12;
      int h = hw >> 6, ww2 = hw & 63;
      int hs = sh_next ? (h + 60) & 63 : h;
      int ws = sh_next ? (ww2 + 60) & 63 : ww2;
      int win = ((hs >> 3) << 3) | (ws >> 3);
      int n64 = ((hs & 7) << 3) | (ws & 7);
      size_t drow = ((size_t)gi << 12) + (win << 6) + n64;
      unsigned short* op = lnout + drow * DIM;
#pragma unroll
      for (int n = 0; n < 12; ++n)
        op[(n << 4) + ecol] = f2bf((v[n] - mu) * rs * gv[n] + bev[n]);
    } else {
      unsigned short* op = lnout + (size_t)tok * DIM;
#pragma unroll
      for (int n = 0; n < 12; ++n) {
        float r = (v[n] - mu) * rs * gv[n] + bev[n];
        yp[(n << 4) + ecol] = r;
        op[(n << 4) + ecol] = f2bf(r);
      }
    }
  }
}

// ---------------- conv 3x3 as 9 shifted tap-GEMMs + residual ---------------
__global__ __launch_bounds__(256) void conv_k(
    const unsigned short* __restrict__ A, const unsigned short* __restrict__ W,
    float* __restrict__ out, const float* __restrict__ Z,
    const unsigned short* __restrict__ zpg) {
  __shared__ unsigned short As[128 * 64];
  __shared__ unsigned short Bs[64 * 64];
  const int tid = threadIdx.x;
  const int w = tid >> 6, lane = tid & 63;
  const int row0 = blockIdx.x << 7;
  const int col0 = blockIdx.y << 6;
  f32x4 acc[2][4] = {};
  bool first = true;

#pragma unroll
  for (int tap = 0; tap < 9; ++tap) {
    const int dh = tap / 3 - 1, dw = tap % 3 - 1;
#pragma unroll
    for (int k0 = 0; k0 < 192; k0 += 64) {
      if (!first) __syncthreads();
      first = false;
#pragma unroll
      for (int r = 0; r < 2; ++r) {
        int q = (r << 8) + tid;
        int brow = q >> 3, cs = q & 7;
        int kg = cs ^ (brow & 7);
        GLD(W + (size_t)(col0 + brow) * 1728 + tap * 192 + k0 + (kg << 3),
            Bs + (((r << 8) + (w << 6)) << 3));
      }
#pragma unroll
      for (int r = 0; r < 4; ++r) {
        int q = (r << 8) + tid;
        int arow = q >> 3, cs = q & 7;
        int kg = cs ^ (arow & 7);
        int m = row0 + arow;
        int hw_ = m & 4095;
        int h = hw_ >> 6, ww = hw_ & 63;
        int ih = h + dh, iw = ww + dw;
        const unsigned short* src =
            ((unsigned)ih < 64u && (unsigned)iw < 64u)
                ? A + (size_t)(m + dh * 64 + dw) * DIM + k0 + (kg << 3)
                : zpg;
        GLD(src, As + (((r << 8) + (w << 6)) << 3));
      }
      __syncthreads();
      mfma_block128(As, Bs, acc, w, lane);
    }
  }

  const int erow = (lane >> 4) << 2;
  const int ecol = lane & 15;
#pragma unroll
  for (int mr = 0; mr < 2; ++mr)
#pragma unroll
    for (int nr = 0; nr < 4; ++nr)
#pragma unroll
      for (int j = 0; j < 4; ++j) {
        int row = row0 + (w << 5) + (mr << 4) + erow + j;  // global token
        int col = col0 + (nr << 4) + ecol;
        int b = row >> 12, hw_ = row & 4095;
        out[(((size_t)(b * DIM + col)) << 12) + hw_] =
            acc[mr][nr][j] + Z[(size_t)row * DIM + col];
      }
}

// ---------------------------------------------------------------------------
extern "C" void kernel_launch(void* const* d_in, const int* in_sizes, int n_in,
                              void* d_out, int out_size, void* d_ws,
                              size_t ws_size, hipStream_t stream) {
  const float* x = (const float*)d_in[0];
  const float* en_g = (const float*)d_in[1];
  const float* en_b = (const float*)d_in[2];
  const float* n1_g = (const float*)d_in[3];
  const float* n1_b = (const float*)d_in[4];
  const float* qkv_w = (const float*)d_in[5];
  const float* qkv_b = (const float*)d_in[6];
  const float* proj_w = (const float*)d_in[7];
  const float* proj_b = (const float*)d_in[8];
  const float* rpb = (const float*)d_in[9];
  const float* n2_g = (const float*)d_in[10];
  const float* n2_b = (const float*)d_in[11];
  const float* fc1_w = (const float*)d_in[12];
  const float* fc1_b = (const float*)d_in[13];
  const float* fc2_w = (const float*)d_in[14];
  const float* fc2_b = (const float*)d_in[15];
  const float* fn_g = (const float*)d_in[16];
  const float* fn_b = (const float*)d_in[17];
  const float* conv_w = (const float*)d_in[18];
  float* out = (float*)d_out;

  // workspace layout (bytes):
  //   y      @ 0          fp32 [65536,192]             50331648
  //   buf1a  @ 50331648   bf16 [65536,192]             25165824
  //   buf1b  @ 75497472   bf16 [65536,192]             25165824
  //   wbuf   @ 100663296  bf16 weights                  5971968
  //   zpg    @ 106635264  zero page                         256
  //   qkv_bs @ 106635520  scaled qkv bias fp32            13824  -> 106.65MB
  // qkv scratch = d_out (50.3MB >= 37.7MB needed; fully overwritten by
  // conv_k at the end of every call -> graph-safe).
  float* y = (float*)d_ws;
  unsigned short* buf1a = (unsigned short*)((char*)d_ws + 50331648);
  unsigned short* buf1b = (unsigned short*)((char*)d_ws + 75497472);
  unsigned short* wbuf = (unsigned short*)((char*)d_ws + 100663296);
  unsigned short* zpg = (unsigned short*)((char*)d_ws + 106635264);
  float* qkv_bs = (float*)((char*)d_ws + 106635520);
  unsigned short* qkvbuf = (unsigned short*)d_out;

  unsigned short* qkv_wb = wbuf;             // 6*576*192  = 663552
  unsigned short* proj_wb = wbuf + 663552;   // 6*192*192  = 221184
  unsigned short* fc1_wb = wbuf + 884736;    // 6*768*192  = 884736
  unsigned short* fc2_wb = wbuf + 1769472;   // 6*192*768  = 884736
  unsigned short* conv_wb = wbuf + 2654208;  // 192*1728   = 331776

  zero_k<<<1, 64, 0, stream>>>((float*)zpg);
  cvt_qkv_k<<<2592, 256, 0, stream>>>(qkv_w, qkv_wb);
  scale_qkvb_k<<<14, 256, 0, stream>>>(qkv_b, qkv_bs);
  cvt_k<<<216, 256, 0, stream>>>(proj_w, proj_wb, 221184);
  cvt_k<<<864, 256, 0, stream>>>(fc1_w, fc1_wb, 884736);
  cvt_k<<<864, 256, 0, stream>>>(fc2_w, fc2_wb, 884736);
  cvt_conv_k<<<1296, 256, 0, stream>>>(conv_w, conv_wb);

  embed_ln_t_k<<<1024, 256, 0, stream>>>(x, en_g, en_b, y);
  // block 0 LN1 + window partition (sh = 0) -> buf1a
  ln_window_k<<<16384, 256, 0, stream>>>(y, n1_g, n1_b, buf1a, 0);

  for (int i = 0; i < 6; ++i) {
    int sh = i & 1;
    unsigned short* bufA = (i & 1) ? buf1b : buf1a;
    unsigned short* bufB = (i & 1) ? buf1a : buf1b;
    // qkv + attention in 2 chunks (qkv scratch = d_out)
    for (int c = 0; c < 2; ++c) {
      unsigned short* bAc = bufA + (size_t)c * CHQ * DIM;
      mgemm_k<3><<<dim3(CHQ / 256, 9), 256, 0, stream>>>(
          bAc, qkv_wb + (size_t)i * QKV_D * DIM, qkv_bs + i * QKV_D, qkvbuf,
          QKV_D, DIM);
      attn_k<<<(CHQ / 64) * HEADS, 64, 0, stream>>>(
          qkvbuf, rpb + i * 225 * HEADS, bAc, sh, c * (CHQ / 64));
    }
    // fused proj + LN2 + MLP + LN1next (LAST: final LN fused)
    if (i < 5) {
      pm_k<0><<<TOK / 64, 256, 0, stream>>>(
          bufA, proj_wb + (size_t)i * DIM * DIM, proj_b + i * DIM,
          n2_g + i * DIM, n2_b + i * DIM, fc1_wb + (size_t)i * MLP_D * DIM,
          fc1_b + i * MLP_D, fc2_wb + (size_t)i * DIM * MLP_D, fc2_b + i * DIM,
          y, bufB, n1_g + (i + 1) * DIM, n1_b + (i + 1) * DIM, sh, (i + 1) & 1);
    } else {
      pm_k<1><<<TOK / 64, 256, 0, stream>>>(
          bufA, proj_wb + (size_t)i * DIM * DIM, proj_b + i * DIM,
          n2_g + i * DIM, n2_b + i * DIM, fc1_wb + (size_t)i * MLP_D * DIM,
          fc1_b + i * MLP_D, fc2_wb + (size_t)i * DIM * MLP_D, fc2_b + i * DIM,
          y, bufB, fn_g, fn_b, sh, 0);
    }
  }

  // tail: single conv dispatch (A = buf1a bf16 LN'd, Z = y fp32 LN'd)
  conv_k<<<dim3(TOK / 128, 3), 256, 0, stream>>>(buf1a, conv_wb, out, y, zpg);
}

// Round 22
// 1152.489 us; speedup vs baseline: 1.2812x; 1.0127x over previous
//
#include <hip/hip_runtime.h>
#include <cstdint>
#include <cstddef>

// Problem constants
#define BATCH 16
#define DIM 192
#define HEADS 6
#define HD 32
#define TOK 65536
#define QKV_D 576
#define MLP_D 768
#define SCALE 0.17677669529663687f  // 32^-0.5

#define CHQ 32768    // chunk for qkv+attention phase (8 images)

typedef __bf16 bf16x8 __attribute__((ext_vector_type(8)));
typedef float f32x4 __attribute__((ext_vector_type(4)));

__device__ __forceinline__ unsigned short f2bf(float f) {
  union { float f; unsigned u; } c;
  c.f = f;
  return (unsigned short)((c.u + 0x7fffu + ((c.u >> 16) & 1)) >> 16);
}

__device__ __forceinline__ float waveSum(float v) {
#pragma unroll
  for (int off = 32; off; off >>= 1) v += __shfl_xor(v, off, 64);
  return v;
}

// reduce across the 16 lanes sharing a C-row (lane>>4 fixed)
__device__ __forceinline__ float rowSum16(float v) {
  v += __shfl_xor(v, 1, 64);
  v += __shfl_xor(v, 2, 64);
  v += __shfl_xor(v, 4, 64);
  v += __shfl_xor(v, 8, 64);
  return v;
}

// global -> LDS direct (16B/lane). LDS dest wave-uniform base + lane*16.
#define GLD(SRC, DST)                                                     \
  __builtin_amdgcn_global_load_lds(                                       \
      (const __attribute__((address_space(1))) void*)(SRC),               \
      (__attribute__((address_space(3))) void*)(DST), 16, 0, 0)

// ---------------- merged setup: weight cvt + bias scale + zero page --------
// grid layout: [0,2592) qkv cvt | [2592,2808) proj | [2808,3672) fc1 |
// [3672,4536) fc2 | [4536,5832) conv | [5832,5846) qkv bias | 5846 zero
__global__ __launch_bounds__(256) void setup_k(
    const float* __restrict__ qkv_w, const float* __restrict__ qkv_b,
    const float* __restrict__ proj_w, const float* __restrict__ fc1_w,
    const float* __restrict__ fc2_w, const float* __restrict__ conv_w,
    unsigned short* __restrict__ qkv_wb, float* __restrict__ qkv_bs,
    unsigned short* __restrict__ proj_wb, unsigned short* __restrict__ fc1_wb,
    unsigned short* __restrict__ fc2_wb, unsigned short* __restrict__ conv_wb,
    float* __restrict__ zpg) {
  const int bid = blockIdx.x;
  const int tid = threadIdx.x;
  if (bid < 2592) {  // qkv weights, Q rows pre-scaled
    int i = (bid << 8) + tid;
    if (i < 663552) {
      int r = (i / 192) % 576;
      float v = qkv_w[i];
      if (r < 192) v *= SCALE;
      qkv_wb[i] = f2bf(v);
    }
  } else if (bid < 2808) {  // proj, vec4
    int i = ((((bid - 2592) << 8) + tid) << 2);
    if (i < 221184) {
      float4 v = *(const float4*)(proj_w + i);
      proj_wb[i] = f2bf(v.x);
      proj_wb[i + 1] = f2bf(v.y);
      proj_wb[i + 2] = f2bf(v.z);
      proj_wb[i + 3] = f2bf(v.w);
    }
  } else if (bid < 3672) {  // fc1, vec4
    int i = ((((bid - 2808) << 8) + tid) << 2);
    if (i < 884736) {
      float4 v = *(const float4*)(fc1_w + i);
      fc1_wb[i] = f2bf(v.x);
      fc1_wb[i + 1] = f2bf(v.y);
      fc1_wb[i + 2] = f2bf(v.z);
      fc1_wb[i + 3] = f2bf(v.w);
    }
  } else if (bid < 4536) {  // fc2, vec4
    int i = ((((bid - 3672) << 8) + tid) << 2);
    if (i < 884736) {
      float4 v = *(const float4*)(fc2_w + i);
      fc2_wb[i] = f2bf(v.x);
      fc2_wb[i + 1] = f2bf(v.y);
      fc2_wb[i + 2] = f2bf(v.z);
      fc2_wb[i + 3] = f2bf(v.w);
    }
  } else if (bid < 5832) {  // conv, tap-major transpose
    int i = ((bid - 4536) << 8) + tid;
    if (i < 331776) {
      int o = i / 1728;
      int r = i - o * 1728;
      int tap = r / 192;
      int ci = r - tap * 192;
      conv_wb[i] = f2bf(conv_w[o * 1728 + ci * 9 + tap]);
    }
  } else if (bid < 5846) {  // qkv bias scaled
    int i = ((bid - 5832) << 8) + tid;
    if (i < 3456) {
      float v = qkv_b[i];
      if ((i % 576) < 192) v *= SCALE;
      qkv_bs[i] = v;
    }
  } else {  // zero page
    if (tid < 64) zpg[tid] = 0.f;
  }
}

// ---------------- patch embed LN + LN1(block0) + window partition ----------
// x[B,192,4096] -> y fp32 token rows AND buf1a bf16 window rows (sh=0).
__global__ __launch_bounds__(256) void embed_ln_t_k(
    const float* __restrict__ x, const float* __restrict__ g,
    const float* __restrict__ be, float* __restrict__ y,
    const float* __restrict__ g1, const float* __restrict__ be1,
    unsigned short* __restrict__ xw) {
  __shared__ float ts[192 * 65];
  const int w = threadIdx.x >> 6, lane = threadIdx.x & 63;
  const int t0 = blockIdx.x << 6;
  const int b = t0 >> 12, tb = t0 & 4095;
  const float* xb = x + (((size_t)b * DIM) << 12) + tb;
#pragma unroll
  for (int j = 0; j < 48; ++j) {
    int ch = w * 48 + j;
    ts[ch * 65 + lane] = xb[((size_t)ch << 12) + lane];
  }
  __syncthreads();
#pragma unroll 4
  for (int idx = 0; idx < 16; ++idx) {
    int tk = (w << 4) + idx;
    float v0 = ts[lane * 65 + tk];
    float v1 = ts[(lane + 64) * 65 + tk];
    float v2 = ts[(lane + 128) * 65 + tk];
    float mu = waveSum(v0 + v1 + v2) * (1.f / 192.f);
    float d0 = v0 - mu, d1 = v1 - mu, d2 = v2 - mu;
    float var = waveSum(d0 * d0 + d1 * d1 + d2 * d2) * (1.f / 192.f);
    float rs = rsqrtf(var + 1e-5f);
    int tok = t0 + tk;
    float* yp = y + (size_t)tok * DIM;
    float r0 = d0 * rs * g[lane] + be[lane];
    float r1 = d1 * rs * g[lane + 64] + be[lane + 64];
    float r2 = d2 * rs * g[lane + 128] + be[lane + 128];
    yp[lane] = r0;
    yp[lane + 64] = r1;
    yp[lane + 128] = r2;
    // fused LN1 (block 0, sh=0) on the same register row -> window scatter
    float mu1 = waveSum(r0 + r1 + r2) * (1.f / 192.f);
    float e0 = r0 - mu1, e1 = r1 - mu1, e2 = r2 - mu1;
    float var1 = waveSum(e0 * e0 + e1 * e1 + e2 * e2) * (1.f / 192.f);
    float rs1 = rsqrtf(var1 + 1e-5f);
    int hw = tok & 4095;
    int h = hw >> 6, ww = hw & 63;
    int win = ((h >> 3) << 3) | (ww >> 3);
    int n64 = ((h & 7) << 3) | (ww & 7);
    int m = (((tok >> 12) << 6) + win) * 64 + n64;
    unsigned short* op = xw + (size_t)m * DIM;
    op[lane] = f2bf(e0 * rs1 * g1[lane] + be1[lane]);
    op[lane + 64] = f2bf(e1 * rs1 * g1[lane + 64] + be1[lane + 64]);
    op[lane + 128] = f2bf(e2 * rs1 * g1[lane + 128] + be1[lane + 128]);
  }
}

// ---------------- MFMA windowed attention: 1 wave per (window, head) -------
__global__ __launch_bounds__(64) void attn_k(
    const unsigned short* __restrict__ qkv, const float* __restrict__ rpb,
    unsigned short* __restrict__ out, int shifted, int widx0) {
  __shared__ unsigned short vt[32 * 72];
  __shared__ unsigned short pl[64 * 72];
  __shared__ float rp[228];
  const int lwidx = blockIdx.x / HEADS;
  const int head = blockIdx.x - lwidx * HEADS;
  const int l = threadIdx.x;
  const int g = l >> 4, li = l & 15;

  for (int i = l; i < 225; i += 64) rp[i] = rpb[i * HEADS + head];

  const unsigned short* base = qkv + (size_t)lwidx * 64 * QKV_D + head * HD;

  bf16x8 qf[4], kf[4];
#pragma unroll
  for (int n = 0; n < 4; ++n)
    qf[n] = *(const bf16x8*)(base + (size_t)(16 * n + li) * QKV_D + g * 8);
#pragma unroll
  for (int i = 0; i < 4; ++i)
    kf[i] = *(const bf16x8*)(base + (size_t)(16 * i + li) * QKV_D + DIM + g * 8);

#pragma unroll
  for (int p = 0; p < 4; ++p) {
    int r = 16 * p + (l >> 2);
    int d0 = (l & 3) << 3;
    bf16x8 v8 = *(const bf16x8*)(base + (size_t)r * QKV_D + 2 * DIM + d0);
#pragma unroll
    for (int e = 0; e < 8; ++e)
      vt[(d0 + e) * 72 + r] = ((const unsigned short*)&v8)[e];
  }

  f32x4 s[4][4] = {};
#pragma unroll
  for (int i = 0; i < 4; ++i)
#pragma unroll
    for (int n = 0; n < 4; ++n)
      s[i][n] = __builtin_amdgcn_mfma_f32_16x16x32_bf16(kf[i], qf[n], s[i][n],
                                                        0, 0, 0);
  __syncthreads();

  const int win = (widx0 + lwidx) & 63;
  const int wh = (win >> 3) << 3, wwp = (win & 7) << 3;
  int rq[4], cq[4], zq[4];
#pragma unroll
  for (int n = 0; n < 4; ++n) {
    int q = 16 * n + li;
    rq[n] = q >> 3;
    cq[n] = q & 7;
    zq[n] = 0;
    if (shifted) {
      int hq = wh + rq[n], wq = wwp + cq[n];
      int zr = hq < 56 ? 0 : (hq < 60 ? 1 : 2);
      int zc = wq < 56 ? 0 : (wq < 60 ? 1 : 2);
      zq[n] = 3 * zr + zc;
    }
  }
#pragma unroll
  for (int i = 0; i < 4; ++i)
#pragma unroll
    for (int j = 0; j < 4; ++j) {
      int m = 16 * i + 4 * g + j;
      int rm = m >> 3, cm = m & 7;
      int zm = 0;
      if (shifted) {
        int hm = wh + rm, wm = wwp + cm;
        int zr = hm < 56 ? 0 : (hm < 60 ? 1 : 2);
        int zc = wm < 56 ? 0 : (wm < 60 ? 1 : 2);
        zm = 3 * zr + zc;
      }
#pragma unroll
      for (int n = 0; n < 4; ++n) {
        float b = rp[(rq[n] - rm + 7) * 15 + (cq[n] - cm + 7)];
        if (shifted && zm != zq[n]) b -= 100.f;
        s[i][n][j] += b;
      }
    }

  float inv[4];
#pragma unroll
  for (int n = 0; n < 4; ++n) {
    float m0 = -1e30f;
#pragma unroll
    for (int i = 0; i < 4; ++i)
#pragma unroll
      for (int j = 0; j < 4; ++j) m0 = fmaxf(m0, s[i][n][j]);
    m0 = fmaxf(m0, __shfl_xor(m0, 16, 64));
    m0 = fmaxf(m0, __shfl_xor(m0, 32, 64));
    float s0 = 0.f;
#pragma unroll
    for (int i = 0; i < 4; ++i)
#pragma unroll
      for (int j = 0; j < 4; ++j) {
        float e = __expf(s[i][n][j] - m0);
        s[i][n][j] = e;
        s0 += e;
      }
    s0 += __shfl_xor(s0, 16, 64);
    s0 += __shfl_xor(s0, 32, 64);
    inv[n] = 1.f / s0;
  }

#pragma unroll
  for (int n = 0; n < 4; ++n) {
    int q = 16 * n + li;
#pragma unroll
    for (int i = 0; i < 4; ++i) {
      unsigned lo = (unsigned)f2bf(s[i][n][0]) | ((unsigned)f2bf(s[i][n][1]) << 16);
      unsigned hi = (unsigned)f2bf(s[i][n][2]) | ((unsigned)f2bf(s[i][n][3]) << 16);
      *(uint2*)&pl[q * 72 + 16 * i + 4 * g] = uint2{lo, hi};
    }
  }
  __syncthreads();

  f32x4 o[2][4] = {};
#pragma unroll
  for (int ks = 0; ks < 2; ++ks) {
    bf16x8 va[2], pb[4];
#pragma unroll
    for (int i2 = 0; i2 < 2; ++i2)
      va[i2] = *(const bf16x8*)&vt[(16 * i2 + li) * 72 + 32 * ks + 8 * g];
#pragma unroll
    for (int n2 = 0; n2 < 4; ++n2)
      pb[n2] = *(const bf16x8*)&pl[(16 * n2 + li) * 72 + 32 * ks + 8 * g];
#pragma unroll
    for (int i2 = 0; i2 < 2; ++i2)
#pragma unroll
      for (int n2 = 0; n2 < 4; ++n2)
        o[i2][n2] = __builtin_amdgcn_mfma_f32_16x16x32_bf16(va[i2], pb[n2],
                                                            o[i2][n2], 0, 0, 0);
  }

  unsigned short* ob = out + (size_t)(lwidx * 64) * DIM + head * HD;
#pragma unroll
  for (int i2 = 0; i2 < 2; ++i2)
#pragma unroll
    for (int n2 = 0; n2 < 4; ++n2) {
      int q = 16 * n2 + li;
      float iv = inv[n2];
      unsigned lo = (unsigned)f2bf(o[i2][n2][0] * iv) |
                    ((unsigned)f2bf(o[i2][n2][1] * iv) << 16);
      unsigned hi = (unsigned)f2bf(o[i2][n2][2] * iv) |
                    ((unsigned)f2bf(o[i2][n2][3] * iv) << 16);
      *(uint2*)(ob + (size_t)q * DIM + 16 * i2 + 4 * g) = uint2{lo, hi};
    }
}

// ---------------- MFMA inner block (256x64 tile, BK=64, 4 waves x 64x64) ---
__device__ __forceinline__ void mfma_block256(const unsigned short* As,
                                              const unsigned short* Bs,
                                              f32x4 acc[4][4], int w,
                                              int lane) {
  const int frow = lane & 15;
  const int fk = (lane >> 4) << 3;
#pragma unroll
  for (int kk = 0; kk < 64; kk += 32) {
    int slotk = (kk + fk) >> 3;
    bf16x8 a[4], b[4];
#pragma unroll
    for (int m = 0; m < 4; ++m) {
      int ar = (w << 6) + (m << 4) + frow;
      a[m] = *(const bf16x8*)&As[(ar << 6) + ((slotk ^ (ar & 7)) << 3)];
    }
#pragma unroll
    for (int n = 0; n < 4; ++n) {
      int br = (n << 4) + frow;
      b[n] = *(const bf16x8*)&Bs[(br << 6) + ((slotk ^ (br & 7)) << 3)];
    }
#pragma unroll
    for (int m = 0; m < 4; ++m)
#pragma unroll
      for (int n = 0; n < 4; ++n)
        acc[m][n] =
            __builtin_amdgcn_mfma_f32_16x16x32_bf16(a[m], b[n], acc[m][n], 0,
                                                    0, 0);
  }
}

// ---------------- MFMA inner block (128x64 tile, 4 waves x 32x64) ----------
__device__ __forceinline__ void mfma_block128(const unsigned short* As,
                                              const unsigned short* Bs,
                                              f32x4 acc[2][4], int w,
                                              int lane) {
  const int frow = lane & 15;
  const int fk = (lane >> 4) << 3;
#pragma unroll
  for (int kk = 0; kk < 64; kk += 32) {
    int slotk = (kk + fk) >> 3;
    int ar0 = (w << 5) + frow, ar1 = ar0 + 16;
    bf16x8 a0 = *(const bf16x8*)&As[(ar0 << 6) + ((slotk ^ (ar0 & 7)) << 3)];
    bf16x8 a1 = *(const bf16x8*)&As[(ar1 << 6) + ((slotk ^ (ar1 & 7)) << 3)];
    bf16x8 b[4];
#pragma unroll
    for (int n = 0; n < 4; ++n) {
      int br = (n << 4) + frow;
      b[n] = *(const bf16x8*)&Bs[(br << 6) + ((slotk ^ (br & 7)) << 3)];
    }
#pragma unroll
    for (int n = 0; n < 4; ++n) {
      acc[0][n] = __builtin_amdgcn_mfma_f32_16x16x32_bf16(a0, b[n], acc[0][n], 0, 0, 0);
      acc[1][n] = __builtin_amdgcn_mfma_f32_16x16x32_bf16(a1, b[n], acc[1][n], 0, 0, 0);
    }
  }
}

// ---------------- MFMA bf16 GEMM (N-tiled): bf16 out (QKV) -----------------
template <int EPI>
__global__ __launch_bounds__(256) void mgemm_k(
    const unsigned short* __restrict__ A, const unsigned short* __restrict__ W,
    const float* __restrict__ bias, void* __restrict__ Cv, int N, int K) {
  __shared__ unsigned short As[256 * 64];
  __shared__ unsigned short Bs[64 * 64];
  const int tid = threadIdx.x;
  const int w = tid >> 6, lane = tid & 63;
  const int row0 = blockIdx.x << 8;
  const int col0 = blockIdx.y << 6;
  f32x4 acc[4][4] = {};

  for (int k0 = 0; k0 < K; k0 += 64) {
    if (k0) __syncthreads();
#pragma unroll
    for (int r = 0; r < 2; ++r) {
      int q = (r << 8) + tid;
      int brow = q >> 3, cs = q & 7;
      int kg = cs ^ (brow & 7);
      GLD(W + (size_t)(col0 + brow) * K + k0 + (kg << 3),
          Bs + (((r << 8) + (w << 6)) << 3));
    }
#pragma unroll
    for (int r = 0; r < 8; ++r) {
      int q = (r << 8) + tid;
      int arow = q >> 3, cs = q & 7;
      int kg = cs ^ (arow & 7);
      GLD(A + (size_t)(row0 + arow) * K + k0 + (kg << 3),
          As + (((r << 8) + (w << 6)) << 3));
    }
    __syncthreads();
    mfma_block256(As, Bs, acc, w, lane);
  }

  const int erow = (lane >> 4) << 2;
  const int ecol = lane & 15;
#pragma unroll
  for (int mr = 0; mr < 4; ++mr)
#pragma unroll
    for (int nr = 0; nr < 4; ++nr)
#pragma unroll
      for (int j = 0; j < 4; ++j) {
        int row = row0 + (w << 6) + (mr << 4) + erow + j;
        int col = col0 + (nr << 4) + ecol;
        float v = acc[mr][nr][j];
        ((unsigned short*)Cv)[(size_t)row * N + col] = f2bf(v + bias[col]);
      }
}

// ---------------- fused proj + LN2 + MLP + LN1next (pm_k) ------------------
// Block = 64 window-rows. Proj with A-frags in registers; y-residual + LN2
// in-register; LN2 -> a2 LDS (wave-local) -> ap regs; MLP with dual W bufs.
// LAST=0: y = residual (fp32), LN1(next parity) -> lnout window row.
// LAST=1: final LN fused: y = LN(residual) fp32, lnout[tok] = bf16 LN.
template <int LAST>
__global__ __launch_bounds__(256) void pm_k(
    const unsigned short* __restrict__ A, const unsigned short* __restrict__ Wp,
    const float* __restrict__ bp, const float* __restrict__ g2,
    const float* __restrict__ be2, const unsigned short* __restrict__ W1,
    const float* __restrict__ b1, const unsigned short* __restrict__ W2,
    const float* __restrict__ b2, float* __restrict__ y,
    unsigned short* __restrict__ lnout, const float* __restrict__ g1,
    const float* __restrict__ be1, int sh_cur, int sh_next) {
  __shared__ unsigned short a2[64 * 192];   // ln2 rows, 3x[64][64] swizzled
  __shared__ unsigned short Wb1[64 * 192];  // W1 slice (3x[64][64])
  __shared__ unsigned short Wb2[192 * 64];  // Wp k0-slice / W2 slice [192][64]
  __shared__ unsigned short hc[64 * 64];
  const int tid = threadIdx.x;
  const int w = tid >> 6, lane = tid & 63;
  const int row0 = blockIdx.x << 6;
  const int frow = lane & 15;
  const int fk = (lane >> 4) << 3;
  const int erow = (lane >> 4) << 2;
  const int ecol = lane & 15;

  // A fragments in registers (wave rows (w<<4)+frow, 6 k-frags of 8)
  bf16x8 ap[6];
  {
    const unsigned short* arp = A + (size_t)(row0 + (w << 4) + frow) * 192 + fk;
#pragma unroll
    for (int t = 0; t < 6; ++t) ap[t] = *(const bf16x8*)(arp + t * 32);
  }

  // ---- proj: accp = A @ Wp^T ----
  f32x4 accp[12] = {};
#pragma unroll
  for (int k0 = 0; k0 < 192; k0 += 64) {
    __syncthreads();
#pragma unroll
    for (int r = 0; r < 6; ++r) {
      int q = (r << 8) + tid;
      int rw = q >> 3, cs = q & 7;
      int kg = cs ^ (rw & 7);
      GLD(Wp + (size_t)rw * 192 + k0 + (kg << 3),
          Wb2 + (((r << 8) + (w << 6)) << 3));
    }
    __syncthreads();
#pragma unroll
    for (int kk2 = 0; kk2 < 64; kk2 += 32) {
      int slotk = (kk2 + fk) >> 3;
      int t = (k0 + kk2) >> 5;
#pragma unroll
      for (int n = 0; n < 12; ++n) {
        int br = (n << 4) + frow;
        bf16x8 b = *(const bf16x8*)&Wb2[(br << 6) + ((slotk ^ (br & 7)) << 3)];
        accp[n] =
            __builtin_amdgcn_mfma_f32_16x16x32_bf16(ap[t], b, accp[n], 0, 0, 0);
      }
    }
  }

  // ---- y-residual + LN2 -> a2 (wave-local rows; vp kept in accp) ----
  int tokj[4];
  {
    float bpv[12], gv2[12], bv2[12];
#pragma unroll
    for (int n = 0; n < 12; ++n) {
      int col = (n << 4) + ecol;
      bpv[n] = bp[col];
      gv2[n] = g2[col];
      bv2[n] = be2[col];
    }
#pragma unroll
    for (int j = 0; j < 4; ++j) {
      int m = row0 + (w << 4) + erow + j;
      int n64 = m & 63, widx = m >> 6;
      int bl = widx >> 6, win = widx & 63;
      int hp = ((win >> 3) << 3) + (n64 >> 3);
      int wp2 = ((win & 7) << 3) + (n64 & 7);
      if (sh_cur) { hp = (hp + 4) & 63; wp2 = (wp2 + 4) & 63; }
      int tok = (bl << 12) + (hp << 6) + wp2;
      tokj[j] = tok;
      const float* yp = y + (size_t)tok * DIM;
      float s0 = 0.f;
#pragma unroll
      for (int n = 0; n < 12; ++n) {
        float v = accp[n][j] + bpv[n] + yp[(n << 4) + ecol];
        accp[n][j] = v;
        s0 += v;
      }
      float mu = rowSum16(s0) * (1.f / 192.f);
      float s1 = 0.f;
#pragma unroll
      for (int n = 0; n < 12; ++n) {
        float d = accp[n][j] - mu;
        s1 += d * d;
      }
      float rs = rsqrtf(rowSum16(s1) * (1.f / 192.f) + 1e-5f);
      int hr = (w << 4) + erow + j;
#pragma unroll
      for (int n = 0; n < 12; ++n) {
        int col = (n << 4) + ecol;
        unsigned short lv = f2bf((accp[n][j] - mu) * rs * gv2[n] + bv2[n]);
        int kb = col >> 6, c64 = col & 63;
        a2[(kb << 12) + (hr << 6) + (((c64 >> 3) ^ (hr & 7)) << 3) + (c64 & 7)] =
            lv;
      }
    }
  }
  // reload ap from a2 (wave-local rows; in-wave LDS ordering suffices)
  {
    int ar = (w << 4) + frow;
#pragma unroll
    for (int t = 0; t < 6; ++t) {
      int kb = t >> 1;
      int slotk = (((t & 1) << 5) + fk) >> 3;
      ap[t] = *(const bf16x8*)&a2[(kb << 12) + (ar << 6) +
                                  ((slotk ^ (ar & 7)) << 3)];
    }
  }

  // ---- MLP: acc2 = fc2(gelu(fc1(ln2))) ----
  f32x4 acc2[12] = {};
  for (int n0 = 0; n0 < 12; ++n0) {
    __syncthreads();  // Wb1/Wb2 free from previous gemms
#pragma unroll
    for (int r = 0; r < 6; ++r) {
      int q = (r << 8) + tid;
      int kb = q >> 9, rw = (q >> 3) & 63, cs = q & 7;
      int kg = cs ^ (rw & 7);
      GLD(W1 + (size_t)(n0 * 64 + rw) * 192 + kb * 64 + (kg << 3),
          Wb1 + (((r << 8) + (w << 6)) << 3));
    }
#pragma unroll
    for (int r = 0; r < 6; ++r) {
      int q = (r << 8) + tid;
      int rw = q >> 3, cs = q & 7;
      int kg = cs ^ (rw & 7);
      GLD(W2 + (size_t)rw * 768 + n0 * 64 + (kg << 3),
          Wb2 + (((r << 8) + (w << 6)) << 3));
    }
    __syncthreads();
    f32x4 acc1[4] = {};
#pragma unroll
    for (int kk = 0; kk < 192; kk += 32) {
      int kb = kk >> 6;
      int slotk = ((kk & 63) + fk) >> 3;
#pragma unroll
      for (int n = 0; n < 4; ++n) {
        int br = (n << 4) + frow;
        bf16x8 b = *(const bf16x8*)&Wb1[(kb << 12) + (br << 6) +
                                        ((slotk ^ (br & 7)) << 3)];
        acc1[n] = __builtin_amdgcn_mfma_f32_16x16x32_bf16(ap[kk >> 5], b,
                                                          acc1[n], 0, 0, 0);
      }
    }
    // tanh-form GELU -> hc (wave-local rows)
#pragma unroll
    for (int n = 0; n < 4; ++n) {
      float bb = b1[n0 * 64 + (n << 4) + ecol];
#pragma unroll
      for (int j = 0; j < 4; ++j) {
        int hr = (w << 4) + erow + j;
        int hcol = (n << 4) + ecol;
        float xg = acc1[n][j] + bb;
        float x3 = xg * xg * xg;
        float t1 = fmaf(0.044715f, x3, xg);
        float e = __expf(t1 * -1.5957691216057308f);
        float hv = xg * __builtin_amdgcn_rcpf(1.f + e);
        hc[(hr << 6) + (((hcol >> 3) ^ (hr & 7)) << 3) + (hcol & 7)] = f2bf(hv);
      }
    }
#pragma unroll
    for (int kk = 0; kk < 64; kk += 32) {
      int slotk = (kk + fk) >> 3;
      int ar = (w << 4) + frow;
      bf16x8 a = *(const bf16x8*)&hc[(ar << 6) + ((slotk ^ (ar & 7)) << 3)];
#pragma unroll
      for (int n = 0; n < 12; ++n) {
        int br = (n << 4) + frow;
        bf16x8 b = *(const bf16x8*)&Wb2[(br << 6) + ((slotk ^ (br & 7)) << 3)];
        acc2[n] =
            __builtin_amdgcn_mfma_f32_16x16x32_bf16(a, b, acc2[n], 0, 0, 0);
      }
    }
  }

  // ---- final: v = vp + fc2 + b2; LAST=0: y=v + LN1next scatter;
  //      LAST=1: y = LN(v) fp32 + token-ordered bf16 ----
  float b2v[12], gv[12], bev[12];
#pragma unroll
  for (int n = 0; n < 12; ++n) {
    int col = (n << 4) + ecol;
    b2v[n] = b2[col];
    gv[n] = g1[col];
    bev[n] = be1[col];
  }
#pragma unroll
  for (int j = 0; j < 4; ++j) {
    int tok = tokj[j];
    float* yp = y + (size_t)tok * DIM;
    float v[12];
    float s0 = 0.f;
#pragma unroll
    for (int n = 0; n < 12; ++n) {
      v[n] = accp[n][j] + acc2[n][j] + b2v[n];
      s0 += v[n];
    }
    float mu = rowSum16(s0) * (1.f / 192.f);
    float s1 = 0.f;
#pragma unroll
    for (int n = 0; n < 12; ++n) {
      float d = v[n] - mu;
      s1 += d * d;
    }
    float rs = rsqrtf(rowSum16(s1) * (1.f / 192.f) + 1e-5f);
    if (LAST == 0) {
#pragma unroll
      for (int n = 0; n < 12; ++n) yp[(n << 4) + ecol] = v[n];
      int hw = tok & 4095, gi = tok >> 12;
      int h = hw >> 6, ww2 = hw & 63;
      int hs = sh_next ? (h + 60) & 63 : h;
      int ws = sh_next ? (ww2 + 60) & 63 : ww2;
      int win = ((hs >> 3) << 3) | (ws >> 3);
      int n64 = ((hs & 7) << 3) | (ws & 7);
      size_t drow = ((size_t)gi << 12) + (win << 6) + n64;
      unsigned short* op = lnout + drow * DIM;
#pragma unroll
      for (int n = 0; n < 12; ++n)
        op[(n << 4) + ecol] = f2bf((v[n] - mu) * rs * gv[n] + bev[n]);
    } else {
      unsigned short* op = lnout + (size_t)tok * DIM;
#pragma unroll
      for (int n = 0; n < 12; ++n) {
        float r = (v[n] - mu) * rs * gv[n] + bev[n];
        yp[(n << 4) + ecol] = r;
        op[(n << 4) + ecol] = f2bf(r);
      }
    }
  }
}

// ---------------- conv 3x3 as 9 shifted tap-GEMMs + residual ---------------
__global__ __launch_bounds__(256) void conv_k(
    const unsigned short* __restrict__ A, const unsigned short* __restrict__ W,
    float* __restrict__ out, const float* __restrict__ Z,
    const unsigned short* __restrict__ zpg) {
  __shared__ unsigned short As[128 * 64];
  __shared__ unsigned short Bs[64 * 64];
  const int tid = threadIdx.x;
  const int w = tid >> 6, lane = tid & 63;
  const int row0 = blockIdx.x << 7;
  const int col0 = blockIdx.y << 6;
  f32x4 acc[2][4] = {};
  bool first = true;

#pragma unroll
  for (int tap = 0; tap < 9; ++tap) {
    const int dh = tap / 3 - 1, dw = tap % 3 - 1;
#pragma unroll
    for (int k0 = 0; k0 < 192; k0 += 64) {
      if (!first) __syncthreads();
      first = false;
#pragma unroll
      for (int r = 0; r < 2; ++r) {
        int q = (r << 8) + tid;
        int brow = q >> 3, cs = q & 7;
        int kg = cs ^ (brow & 7);
        GLD(W + (size_t)(col0 + brow) * 1728 + tap * 192 + k0 + (kg << 3),
            Bs + (((r << 8) + (w << 6)) << 3));
      }
#pragma unroll
      for (int r = 0; r < 4; ++r) {
        int q = (r << 8) + tid;
        int arow = q >> 3, cs = q & 7;
        int kg = cs ^ (arow & 7);
        int m = row0 + arow;
        int hw_ = m & 4095;
        int h = hw_ >> 6, ww = hw_ & 63;
        int ih = h + dh, iw = ww + dw;
        const unsigned short* src =
            ((unsigned)ih < 64u && (unsigned)iw < 64u)
                ? A + (size_t)(m + dh * 64 + dw) * DIM + k0 + (kg << 3)
                : zpg;
        GLD(src, As + (((r << 8) + (w << 6)) << 3));
      }
      __syncthreads();
      mfma_block128(As, Bs, acc, w, lane);
    }
  }

  const int erow = (lane >> 4) << 2;
  const int ecol = lane & 15;
#pragma unroll
  for (int mr = 0; mr < 2; ++mr)
#pragma unroll
    for (int nr = 0; nr < 4; ++nr)
#pragma unroll
      for (int j = 0; j < 4; ++j) {
        int row = row0 + (w << 5) + (mr << 4) + erow + j;  // global token
        int col = col0 + (nr << 4) + ecol;
        int b = row >> 12, hw_ = row & 4095;
        out[(((size_t)(b * DIM + col)) << 12) + hw_] =
            acc[mr][nr][j] + Z[(size_t)row * DIM + col];
      }
}

// ---------------------------------------------------------------------------
extern "C" void kernel_launch(void* const* d_in, const int* in_sizes, int n_in,
                              void* d_out, int out_size, void* d_ws,
                              size_t ws_size, hipStream_t stream) {
  const float* x = (const float*)d_in[0];
  const float* en_g = (const float*)d_in[1];
  const float* en_b = (const float*)d_in[2];
  const float* n1_g = (const float*)d_in[3];
  const float* n1_b = (const float*)d_in[4];
  const float* qkv_w = (const float*)d_in[5];
  const float* qkv_b = (const float*)d_in[6];
  const float* proj_w = (const float*)d_in[7];
  const float* proj_b = (const float*)d_in[8];
  const float* rpb = (const float*)d_in[9];
  const float* n2_g = (const float*)d_in[10];
  const float* n2_b = (const float*)d_in[11];
  const float* fc1_w = (const float*)d_in[12];
  const float* fc1_b = (const float*)d_in[13];
  const float* fc2_w = (const float*)d_in[14];
  const float* fc2_b = (const float*)d_in[15];
  const float* fn_g = (const float*)d_in[16];
  const float* fn_b = (const float*)d_in[17];
  const float* conv_w = (const float*)d_in[18];
  float* out = (float*)d_out;

  // workspace layout (bytes):
  //   y      @ 0          fp32 [65536,192]             50331648
  //   buf1a  @ 50331648   bf16 [65536,192]             25165824
  //   buf1b  @ 75497472   bf16 [65536,192]             25165824
  //   wbuf   @ 100663296  bf16 weights                  5971968
  //   zpg    @ 106635264  zero page                         256
  //   qkv_bs @ 106635520  scaled qkv bias fp32            13824  -> 106.65MB
  // qkv scratch = d_out (50.3MB >= 37.7MB needed; fully overwritten by
  // conv_k at the end of every call -> graph-safe).
  float* y = (float*)d_ws;
  unsigned short* buf1a = (unsigned short*)((char*)d_ws + 50331648);
  unsigned short* buf1b = (unsigned short*)((char*)d_ws + 75497472);
  unsigned short* wbuf = (unsigned short*)((char*)d_ws + 100663296);
  unsigned short* zpg = (unsigned short*)((char*)d_ws + 106635264);
  float* qkv_bs = (float*)((char*)d_ws + 106635520);
  unsigned short* qkvbuf = (unsigned short*)d_out;

  unsigned short* qkv_wb = wbuf;             // 6*576*192  = 663552
  unsigned short* proj_wb = wbuf + 663552;   // 6*192*192  = 221184
  unsigned short* fc1_wb = wbuf + 884736;    // 6*768*192  = 884736
  unsigned short* fc2_wb = wbuf + 1769472;   // 6*192*768  = 884736
  unsigned short* conv_wb = wbuf + 2654208;  // 192*1728   = 331776

  // single merged setup dispatch
  setup_k<<<5847, 256, 0, stream>>>(qkv_w, qkv_b, proj_w, fc1_w, fc2_w, conv_w,
                                    qkv_wb, qkv_bs, proj_wb, fc1_wb, fc2_wb,
                                    conv_wb, (float*)zpg);

  // fused patch-embed LN + block0 LN1 window partition
  embed_ln_t_k<<<1024, 256, 0, stream>>>(x, en_g, en_b, y, n1_g, n1_b, buf1a);

  for (int i = 0; i < 6; ++i) {
    int sh = i & 1;
    unsigned short* bufA = (i & 1) ? buf1b : buf1a;
    unsigned short* bufB = (i & 1) ? buf1a : buf1b;
    // qkv + attention in 2 chunks (qkv scratch = d_out)
    for (int c = 0; c < 2; ++c) {
      unsigned short* bAc = bufA + (size_t)c * CHQ * DIM;
      mgemm_k<3><<<dim3(CHQ / 256, 9), 256, 0, stream>>>(
          bAc, qkv_wb + (size_t)i * QKV_D * DIM, qkv_bs + i * QKV_D, qkvbuf,
          QKV_D, DIM);
      attn_k<<<(CHQ / 64) * HEADS, 64, 0, stream>>>(
          qkvbuf, rpb + i * 225 * HEADS, bAc, sh, c * (CHQ / 64));
    }
    // fused proj + LN2 + MLP + LN1next (LAST: final LN fused)
    if (i < 5) {
      pm_k<0><<<TOK / 64, 256, 0, stream>>>(
          bufA, proj_wb + (size_t)i * DIM * DIM, proj_b + i * DIM,
          n2_g + i * DIM, n2_b + i * DIM, fc1_wb + (size_t)i * MLP_D * DIM,
          fc1_b + i * MLP_D, fc2_wb + (size_t)i * DIM * MLP_D, fc2_b + i * DIM,
          y, bufB, n1_g + (i + 1) * DIM, n1_b + (i + 1) * DIM, sh, (i + 1) & 1);
    } else {
      pm_k<1><<<TOK / 64, 256, 0, stream>>>(
          bufA, proj_wb + (size_t)i * DIM * DIM, proj_b + i * DIM,
          n2_g + i * DIM, n2_b + i * DIM, fc1_wb + (size_t)i * MLP_D * DIM,
          fc1_b + i * MLP_D, fc2_wb + (size_t)i * DIM * MLP_D, fc2_b + i * DIM,
          y, bufB, fn_g, fn_b, sh, 0);
    }
  }

  // tail: single conv dispatch (A = buf1a bf16 LN'd, Z = y fp32 LN'd)
  conv_k<<<dim3(TOK / 128, 3), 256, 0, stream>>>(buf1a, conv_wb, out, y, zpg);
}